// Round 5
// baseline (46892.422 us; speedup 1.0000x reference)
//
#include <hip/hip_runtime.h>
#include <math.h>

#define Bb 8
#define Tt 168
#define Nn 512
#define Cc 32
#define Ll 4
#define Kk 50
#define NCH 4
#define BPC 2                     // batches per chunk (chunk boundary = t==0, no cross-chunk reads)
#define BTc (BPC*Tt)              // 336
#define BTNc ((size_t)BTc*Nn)
#define BTCNc ((size_t)BTc*Cc*Nn)
#define BT (Bb*Tt)
#define BTN ((size_t)Bb*Tt*Nn)
#define BTCN ((size_t)Bb*Tt*Cc*Nn)
#define GRU_P 8                   // n-slices per batch (slice = bid&7 -> one XCD per slice)

__device__ __forceinline__ float sigm(float v) { return 1.0f/(1.0f + expf(-v)); }

__device__ __forceinline__ float sysload(const float* p) {
  return __hip_atomic_load(p, __ATOMIC_RELAXED, __HIP_MEMORY_SCOPE_SYSTEM);
}
__device__ __forceinline__ void sysstore(float* p, float v) {
  __hip_atomic_store(p, v, __ATOMIC_RELAXED, __HIP_MEMORY_SCOPE_SYSTEM);
}
__device__ __forceinline__ int flagload(const int* p) {
  return __hip_atomic_load(p, __ATOMIC_RELAXED, __HIP_MEMORY_SCOPE_SYSTEM);
}
__device__ __forceinline__ void flagstore(int* p, int v) {
  __hip_atomic_store(p, v, __ATOMIC_RELAXED, __HIP_MEMORY_SCOPE_SYSTEM);
}

// ---------------- weight transpose for GRU ----------------
__global__ void k_wt(const float* __restrict__ zl, const float* __restrict__ rl,
                     const float* __restrict__ hl,
                     float* __restrict__ zT, float* __restrict__ rT,
                     float* __restrict__ hxT, float* __restrict__ hhT) {
  int idx = blockIdx.x*256 + threadIdx.x;
  if (idx >= Nn*1024) return;
  int n = idx >> 10, j = idx & 1023;
  zT[j*Nn + n] = zl[idx];
  rT[j*Nn + n] = rl[idx];
  float hv = hl[idx];
  if (j < Nn) hxT[j*Nn + n] = hv;
  else        hhT[(j-Nn)*Nn + n] = hv;
}

// ---------------- adaptive adjacency: softmax(relu(nv1@nv2), axis=1) ----------------
__global__ void k_adp(const float* __restrict__ nv1, const float* __restrict__ nv2,
                      float* __restrict__ adp) {
  int i = blockIdx.x;
  __shared__ float row[512];
  __shared__ float red[256];
  float v1[10];
  #pragma unroll
  for (int k=0;k<10;k++) v1[k] = nv1[i*10+k];
  for (int jj = threadIdx.x; jj < 512; jj += 256) {
    float s = 0.f;
    #pragma unroll
    for (int k=0;k<10;k++) s += v1[k]*nv2[k*Nn + jj];
    row[jj] = fmaxf(s, 0.f);
  }
  __syncthreads();
  float m = fmaxf(row[threadIdx.x], row[threadIdx.x+256]);
  red[threadIdx.x] = m; __syncthreads();
  for (int s=128; s>0; s>>=1) { if (threadIdx.x < s) red[threadIdx.x] = fmaxf(red[threadIdx.x], red[threadIdx.x+s]); __syncthreads(); }
  float mx = red[0]; __syncthreads();
  float e0 = expf(row[threadIdx.x]      - mx);
  float e1 = expf(row[threadIdx.x+256]  - mx);
  red[threadIdx.x] = e0 + e1; __syncthreads();
  for (int s=128; s>0; s>>=1) { if (threadIdx.x < s) red[threadIdx.x] += red[threadIdx.x+s]; __syncthreads(); }
  float inv = 1.f/red[0];
  adp[(size_t)i*Nn + threadIdx.x]       = e0*inv;
  adp[(size_t)i*Nn + threadIdx.x + 256] = e1*inv;
}

// ---------------- input transform: x = conv1x1(input[[0,3,5,6]]) -> (B,T,C,N) ----------------
__global__ void k_intransform(const float* __restrict__ input, const float* __restrict__ skw,
                              const float* __restrict__ skb, float* __restrict__ x) {
  size_t idx = (size_t)blockIdx.x*256 + threadIdx.x;
  if (idx >= BTN) return;
  int n = idx & 511;
  size_t bt = idx >> 9;
  int b = (int)(bt / Tt), t = (int)(bt % Tt);
  size_t chs = (size_t)Tt*Nn;
  size_t base = (((size_t)b*7)*Tt + t)*Nn + n;
  float v0 = input[base + 0*chs];
  float v3 = input[base + 3*chs];
  float v5 = input[base + 5*chs];
  float v6 = input[base + 6*chs];
  float* xp = x + bt*Cc*Nn + n;
  #pragma unroll
  for (int c=0;c<32;c++)
    xp[(size_t)c*Nn] = skb[c] + skw[c*4+0]*v0 + skw[c*4+1]*v3 + skw[c*4+2]*v5 + skw[c*4+3]*v6;
}

// ---------------- fused filter/gate conv1x2 -> xg_q ; gout_q = W0@xg + bias (chunk-local) ----------------
__launch_bounds__(256)
__global__ void k_fgconv(const float* __restrict__ x, const float* __restrict__ fw,
                         const float* __restrict__ fb, const float* __restrict__ gw,
                         const float* __restrict__ gb, const float* __restrict__ gcwl,
                         const float* __restrict__ gcb,
                         float* __restrict__ xg, float* __restrict__ gout, int chunk) {
  __shared__ float sfw[2048], sgw[2048], sw0[1024], sfb[32], sgb[32], sgcb[32];
  for (int l = threadIdx.x; l < 2048; l += 256) { sfw[l] = fw[l]; sgw[l] = gw[l]; }
  for (int l = threadIdx.x; l < 1024; l += 256) sw0[l] = gcwl[(l>>5)*224 + (l&31)];
  if (threadIdx.x < 32) {
    sfb[threadIdx.x] = fb[threadIdx.x];
    sgb[threadIdx.x] = gb[threadIdx.x];
    sgcb[threadIdx.x] = gcb[threadIdx.x];
  }
  __syncthreads();
  size_t idx = (size_t)blockIdx.x*256 + threadIdx.x;
  if (idx >= BTNc) return;
  int n = idx & 511;
  size_t btl = idx >> 9;
  int t = (int)(btl % Tt);
  size_t btg = (size_t)chunk*BTc + btl;
  const float* xp = x + btg*Cc*Nn + n;
  float xl[32], xr[32];
  #pragma unroll
  for (int c=0;c<32;c++) xr[c] = xp[(size_t)c*Nn];
  if (t == 0) {
    #pragma unroll
    for (int c=0;c<32;c++) xl[c] = 0.f;
  } else {
    const float* xq = xp - (size_t)Cc*Nn;
    #pragma unroll
    for (int c=0;c<32;c++) xl[c] = xq[(size_t)c*Nn];
  }
  float xgv[32];
  for (int c=0;c<32;c++) {
    float f = sfb[c], g = sgb[c];
    #pragma unroll
    for (int cp=0;cp<32;cp++) {
      f += xl[cp]*sfw[(c*32+cp)*2] + xr[cp]*sfw[(c*32+cp)*2+1];
      g += xl[cp]*sgw[(c*32+cp)*2] + xr[cp]*sgw[(c*32+cp)*2+1];
    }
    xgv[c] = tanhf(f) * sigm(g);
  }
  float* xgp = xg + btl*Cc*Nn + n;
  #pragma unroll
  for (int c=0;c<32;c++) xgp[(size_t)c*Nn] = xgv[c];
  float* gp = gout + btl*Cc*Nn + n;
  for (int o=0;o<32;o++) {
    float s = sgcb[o];
    #pragma unroll
    for (int c=0;c<32;c++) s += sw0[o*32+c]*xgv[c];
    gp[(size_t)o*Nn] = s;
  }
}

// ---------------- support GEMM (per bt: (32x512)@(512x512)) + gconv-slot epilogue ----------------
__launch_bounds__(256)
__global__ void k_supgemm(const float* __restrict__ X, const float* __restrict__ A,
                          const float* __restrict__ gcw, int pslot,
                          float* __restrict__ Y, float* __restrict__ gout, int storeY) {
  __shared__ float sX[32][33];
  __shared__ float sA[32][128];
  __shared__ float sW[1024];
  int tid = threadIdx.x;
  int bt = blockIdx.x >> 2;
  int n0 = (blockIdx.x & 3) << 7;
  const float* Xp = X + (size_t)bt*Cc*Nn;
  for (int l = tid; l < 1024; l += 256)
    sW[l] = gcw[(l>>5)*224 + pslot*32 + (l&31)];
  int tx = tid & 31, ty = tid >> 5;
  float acc[4][4];
  #pragma unroll
  for (int i=0;i<4;i++) { acc[i][0]=0.f; acc[i][1]=0.f; acc[i][2]=0.f; acc[i][3]=0.f; }
  for (int k0 = 0; k0 < Nn; k0 += 32) {
    {
      int r = tid >> 3, kk = (tid & 7) << 2;
      const float4 v = *reinterpret_cast<const float4*>(Xp + (size_t)r*Nn + k0 + kk);
      sX[r][kk] = v.x; sX[r][kk+1] = v.y; sX[r][kk+2] = v.z; sX[r][kk+3] = v.w;
    }
    #pragma unroll
    for (int i=0;i<4;i++) {
      int l = tid + i*256;
      int r = l >> 5, cg_ = l & 31;
      *reinterpret_cast<float4*>(&sA[r][cg_<<2]) =
        *reinterpret_cast<const float4*>(A + (size_t)(k0+r)*Nn + n0 + (cg_<<2));
    }
    __syncthreads();
    #pragma unroll
    for (int k=0;k<32;k++) {
      float4 bv = *reinterpret_cast<const float4*>(&sA[k][tx<<2]);
      float a0 = sX[(ty<<2)+0][k];
      float a1 = sX[(ty<<2)+1][k];
      float a2 = sX[(ty<<2)+2][k];
      float a3 = sX[(ty<<2)+3][k];
      acc[0][0]+=a0*bv.x; acc[0][1]+=a0*bv.y; acc[0][2]+=a0*bv.z; acc[0][3]+=a0*bv.w;
      acc[1][0]+=a1*bv.x; acc[1][1]+=a1*bv.y; acc[1][2]+=a1*bv.z; acc[1][3]+=a1*bv.w;
      acc[2][0]+=a2*bv.x; acc[2][1]+=a2*bv.y; acc[2][2]+=a2*bv.z; acc[2][3]+=a2*bv.w;
      acc[3][0]+=a3*bv.x; acc[3][1]+=a3*bv.y; acc[3][2]+=a3*bv.z; acc[3][3]+=a3*bv.w;
    }
    __syncthreads();
  }
  if (storeY) {
    float* Yp = Y + (size_t)bt*Cc*Nn + n0 + (tx<<2);
    #pragma unroll
    for (int i=0;i<4;i++)
      *reinterpret_cast<float4*>(Yp + (size_t)((ty<<2)+i)*Nn) =
        make_float4(acc[i][0],acc[i][1],acc[i][2],acc[i][3]);
  }
  #pragma unroll
  for (int i=0;i<4;i++)
    *reinterpret_cast<float4*>(&sA[(ty<<2)+i][tx<<2]) =
      make_float4(acc[i][0],acc[i][1],acc[i][2],acc[i][3]);
  __syncthreads();
  float og[4][4];
  #pragma unroll
  for (int i=0;i<4;i++) { og[i][0]=0.f; og[i][1]=0.f; og[i][2]=0.f; og[i][3]=0.f; }
  #pragma unroll 8
  for (int c=0;c<32;c++) {
    float4 yv = *reinterpret_cast<const float4*>(&sA[c][tx<<2]);
    float w0 = sW[((ty<<2)+0)*32 + c];
    float w1 = sW[((ty<<2)+1)*32 + c];
    float w2 = sW[((ty<<2)+2)*32 + c];
    float w3 = sW[((ty<<2)+3)*32 + c];
    og[0][0]+=w0*yv.x; og[0][1]+=w0*yv.y; og[0][2]+=w0*yv.z; og[0][3]+=w0*yv.w;
    og[1][0]+=w1*yv.x; og[1][1]+=w1*yv.y; og[1][2]+=w1*yv.z; og[1][3]+=w1*yv.w;
    og[2][0]+=w2*yv.x; og[2][1]+=w2*yv.y; og[2][2]+=w2*yv.z; og[2][3]+=w2*yv.w;
    og[3][0]+=w3*yv.x; og[3][1]+=w3*yv.y; og[3][2]+=w3*yv.z; og[3][3]+=w3*yv.w;
  }
  float* gp = gout + (size_t)bt*Cc*Nn + n0 + (tx<<2);
  #pragma unroll
  for (int i=0;i<4;i++) {
    float4 cur = *reinterpret_cast<float4*>(gp + (size_t)((ty<<2)+i)*Nn);
    cur.x += og[i][0]; cur.y += og[i][1]; cur.z += og[i][2]; cur.w += og[i][3];
    *reinterpret_cast<float4*>(gp + (size_t)((ty<<2)+i)*Nn) = cur;
  }
}

// ---------------- skip gather: skipK[b,k,c,t] (+)= xg_q[btl,c,node] ----------------
__global__ void k_skipgather(const float* __restrict__ xg, const int* __restrict__ miss,
                             float* __restrict__ skipK, int chunk, int first) {
  int idx = blockIdx.x*256 + threadIdx.x;
  if (idx >= BPC*Kk*Tt) return;
  int t = idx % Tt;
  int k = (idx / Tt) % Kk;
  int bloc = idx / (Tt*Kk);
  int bg = chunk*BPC + bloc;
  int node = miss[bg*Kk + k];
  const float* xp = xg + (((size_t)bloc*Tt + t)*Cc)*Nn + node;
  float* sp = skipK + (((size_t)bg*Kk + k)*Cc)*Tt + t;
  #pragma unroll
  for (int c=0;c<32;c++) {
    float v = xp[(size_t)c*Nn];
    sp[(size_t)c*Tt] = first ? v : (sp[(size_t)c*Tt] + v);
  }
}

// ---------------- ingru: Xs[t,b,n] = sum_c gout_q*iw + ib ----------------
__global__ void k_ingru(const float* __restrict__ gout, const float* __restrict__ iw,
                        const float* __restrict__ ib2, float* __restrict__ Xs, int chunk) {
  size_t idx = (size_t)blockIdx.x*256 + threadIdx.x;
  if (idx >= BTNc) return;
  int n = idx & 511;
  size_t btl = idx >> 9;
  int b = chunk*BPC + (int)(btl / Tt), t = (int)(btl % Tt);
  const float* gp = gout + btl*Cc*Nn + n;
  float s = ib2[0];
  #pragma unroll
  for (int c=0;c<Cc;c++) s += iw[c]*gp[(size_t)c*Nn];
  Xs[((size_t)t*Bb + b)*Nn + n] = s;
}

// ---------------- x += gout_q (chunk fold) ----------------
__global__ void k_xfold(float* __restrict__ x, const float* __restrict__ gout, int chunk) {
  size_t idx = (size_t)blockIdx.x*256 + threadIdx.x;
  if (idx >= BTCNc) return;
  x[(size_t)chunk*BTCNc + idx] += gout[idx];
}

// ---------------- GRU v4: 64 blocks (8 slices x 8 batches), flag-based sync (no RMW) ----------------
// Each block owns a line-padded flag; arrival = one cache-bypassing store (parallel across
// blocks, no ownership ping-pong). 8 threads poll the 8 producer flags of their batch in
// parallel. Flag values are monotone phase numbers -> no reset race. Data plane: SYSTEM-scope
// bypass loads/stores (correct regardless of block->XCD placement).
__launch_bounds__(512)
__global__ void k_gru4(const float* __restrict__ Xs, const float* __restrict__ input,
                       const float* __restrict__ zT, const float* __restrict__ rT,
                       const float* __restrict__ hxT, const float* __restrict__ hhT,
                       const float* __restrict__ zb, const float* __restrict__ rb,
                       const float* __restrict__ hb,
                       float* __restrict__ h_g, float* __restrict__ xin_g,
                       float* __restrict__ rh_g, float* __restrict__ outs,
                       int* __restrict__ flags) {
  __shared__ float xh[1024];     // [ xin(0:512) | h(512:1024) ] for this batch
  __shared__ float rhl[512];
  const int tid = threadIdx.x;
  const int s   = blockIdx.x & 7;     // n-slice (maps to XCD under round-robin)
  const int b   = blockIdx.x >> 3;    // batch
  const int p   = tid >> 4;           // col-pair 0..31
  const int q   = tid & 15;           // K 16-way split
  const int n   = s*64 + p*2;
  int* myflag = flags + (b*GRU_P + s)*32;

#define SIGNAL_WAIT(v) do { \
    asm volatile("s_waitcnt vmcnt(0)" ::: "memory"); \
    __syncthreads(); \
    if (tid == 0) flagstore(myflag, (v)); \
    if (tid < GRU_P) { \
      const int* fl = flags + (b*GRU_P + tid)*32; \
      while (flagload(fl) < (v)) __builtin_amdgcn_s_sleep(1); \
    } \
    __syncthreads(); \
  } while (0)

  // t=0 init for own cols: h=0, xin=sigm(Xs0*M0)
  if (tid < 64) {
    int nn = s*64 + tid;
    float Xi = Xs[(size_t)b*Nn + nn];
    float Mi = input[(((size_t)b*7+1)*Tt + 0)*Nn + nn];
    sysstore(h_g + b*Nn + nn, 0.f);
    sysstore(xin_g + b*Nn + nn, sigm(Xi*Mi));
  }
  SIGNAL_WAIT(1);

  const float* Wz = zT  + n;
  const float* Wr = rT  + n;
  const float* Wx = hxT + n;
  const float* Wh = hhT + n;
  const float zbv0 = zb[n], zbv1 = zb[n+1];
  const float rbv0 = rb[n], rbv1 = rb[n+1];
  const float hbv0 = hb[n], hbv1 = hb[n+1];

  float z0=0.f, z1=0.f, hx0=0.f, hx1=0.f, h0v=0.f, h1v=0.f;

  for (int t = 0; t < Tt; t++) {
    // stage xin,h -> LDS (system loads: fresh from coherence point)
    xh[tid]       = sysload(xin_g + b*Nn + tid);
    xh[512 + tid] = sysload(h_g   + b*Nn + tid);
    __syncthreads();
    // ---- phase A: z, r (K=1024), hx (K=512) ----
    float az0=0,az1=0,ar0=0,ar1=0;
    #pragma unroll 4
    for (int i=0;i<64;i++) {
      int j = (i<<4) + q;
      float xv = xh[j];
      float2 wz = *reinterpret_cast<const float2*>(Wz + (size_t)j*Nn);
      float2 wr = *reinterpret_cast<const float2*>(Wr + (size_t)j*Nn);
      az0 += xv*wz.x; az1 += xv*wz.y;
      ar0 += xv*wr.x; ar1 += xv*wr.y;
    }
    float ah0=0, ah1=0;
    #pragma unroll 4
    for (int i=0;i<32;i++) {
      int j = (i<<4) + q;
      float xv = xh[j];
      float2 wx = *reinterpret_cast<const float2*>(Wx + (size_t)j*Nn);
      ah0 += xv*wx.x; ah1 += xv*wx.y;
    }
    #pragma unroll
    for (int d=1; d<16; d<<=1) {
      az0 += __shfl_xor(az0, d); az1 += __shfl_xor(az1, d);
      ar0 += __shfl_xor(ar0, d); ar1 += __shfl_xor(ar1, d);
      ah0 += __shfl_xor(ah0, d); ah1 += __shfl_xor(ah1, d);
    }
    if (q == 0) {
      z0 = sigm(az0 + zbv0); z1 = sigm(az1 + zbv1);
      hx0 = ah0; hx1 = ah1;
      h0v = xh[512+n]; h1v = xh[512+n+1];
      float r0 = sigm(ar0 + rbv0), r1 = sigm(ar1 + rbv1);
      sysstore(rh_g + b*Nn + n,     r0*h0v);
      sysstore(rh_g + b*Nn + n + 1, r1*h1v);
    }
    SIGNAL_WAIT(2 + 2*t);
    // stage rh -> LDS
    rhl[tid] = sysload(rh_g + b*Nn + tid);
    __syncthreads();
    // ---- phase B: hh (K=512) + combine ----
    float hh0=0, hh1=0;
    #pragma unroll 4
    for (int i=0;i<32;i++) {
      int m = (i<<4) + q;
      float rv = rhl[m];
      float2 wh = *reinterpret_cast<const float2*>(Wh + (size_t)m*Nn);
      hh0 += rv*wh.x; hh1 += rv*wh.y;
    }
    #pragma unroll
    for (int d=1; d<16; d<<=1) { hh0 += __shfl_xor(hh0,d); hh1 += __shfl_xor(hh1,d); }
    if (q == 0) {
      float ht0 = tanhf(hx0 + hh0 + hbv0);
      float ht1 = tanhf(hx1 + hh1 + hbv1);
      float hn0 = (1.f - z0)*h0v + z0*ht0;
      float hn1 = (1.f - z1)*h1v + z1*ht1;
      *reinterpret_cast<float2*>(outs + ((size_t)t*Bb + b)*Nn + n) = make_float2(hn0, hn1);
      sysstore(h_g + b*Nn + n,     hn0);
      sysstore(h_g + b*Nn + n + 1, hn1);
      if (t+1 < Tt) {
        float Xi0 = Xs[((size_t)(t+1)*Bb + b)*Nn + n];
        float Xi1 = Xs[((size_t)(t+1)*Bb + b)*Nn + n + 1];
        float Mi0 = input[(((size_t)b*7+1)*Tt + (t+1))*Nn + n];
        float Mi1 = input[(((size_t)b*7+1)*Tt + (t+1))*Nn + n + 1];
        sysstore(xin_g + b*Nn + n,     sigm(Xi0*Mi0 + hn0*(1.f - Mi0)));
        sysstore(xin_g + b*Nn + n + 1, sigm(Xi1*Mi1 + hn1*(1.f - Mi1)));
      }
    }
    SIGNAL_WAIT(3 + 2*t);
  }
#undef SIGNAL_WAIT
}

// ---------------- x += outs*rw + rb (after GRU) ----------------
__global__ void k_xre(float* __restrict__ x, const float* __restrict__ outs,
                      const float* __restrict__ rw, const float* __restrict__ rb2) {
  size_t idx = (size_t)blockIdx.x*256 + threadIdx.x;
  if (idx >= BTCN) return;
  int n = idx & 511;
  int c = (int)((idx >> 9) & 31);
  size_t bt = idx >> 14;
  int b = (int)(bt / Tt), t = (int)(bt % Tt);
  float o = outs[((size_t)t*Bb + b)*Nn + n];
  x[idx] += o*rw[c] + rb2[c];
}

// ---------------- head: relu(skipK) -> end1 relu -> end2 ----------------
__launch_bounds__(256)
__global__ void k_head(const float* __restrict__ skipK,
                       const float* __restrict__ e1w, const float* __restrict__ e1b,
                       const float* __restrict__ e2w, const float* __restrict__ e2b,
                       float* __restrict__ out) {
  __shared__ float sw[2048], sb[64], s2[64];
  for (int l = threadIdx.x; l < 2048; l += 256) sw[l] = e1w[l];
  if (threadIdx.x < 64) { sb[threadIdx.x] = e1b[threadIdx.x]; s2[threadIdx.x] = e2w[threadIdx.x]; }
  __syncthreads();
  int idx = blockIdx.x*256 + threadIdx.x;
  if (idx >= Bb*Kk*Tt) return;
  int t = idx % Tt;
  int k = (idx / Tt) % Kk;
  int b = idx / (Tt*Kk);
  const float* sp = skipK + (((size_t)b*Kk + k)*Cc)*Tt + t;
  float in[32];
  #pragma unroll
  for (int c=0;c<32;c++) in[c] = fmaxf(sp[(size_t)c*Tt], 0.f);
  float acc = e2b[0];
  for (int o=0;o<64;o++) {
    float s = sb[o];
    #pragma unroll
    for (int c=0;c<32;c++) s += sw[o*32+c]*in[c];
    acc += s2[o]*fmaxf(s, 0.f);
  }
  out[idx] = acc;
}

extern "C" void kernel_launch(void* const* d_in, const int* in_sizes, int n_in,
                              void* d_out, int out_size, void* d_ws, size_t ws_size,
                              hipStream_t stream) {
  const float* input = (const float*)d_in[0];
  const int*   miss  = (const int*)  d_in[1];
  const float* sup0  = (const float*)d_in[2];
  const float* sup1  = (const float*)d_in[3];
  const float* nv1   = (const float*)d_in[4];
  const float* nv2   = (const float*)d_in[5];
  const float* skw   = (const float*)d_in[6];
  const float* skb   = (const float*)d_in[7];
  const float* fw    = (const float*)d_in[8];
  const float* fb    = (const float*)d_in[9];
  const float* gw    = (const float*)d_in[10];
  const float* gb    = (const float*)d_in[11];
  const float* gcw   = (const float*)d_in[12];
  const float* gcb   = (const float*)d_in[13];
  const float* iw    = (const float*)d_in[14];
  const float* ib2   = (const float*)d_in[15];
  const float* rw    = (const float*)d_in[16];
  const float* rb2   = (const float*)d_in[17];
  const float* zl    = (const float*)d_in[18];
  const float* zb    = (const float*)d_in[19];
  const float* rl    = (const float*)d_in[20];
  const float* rb    = (const float*)d_in[21];
  const float* hl    = (const float*)d_in[22];
  const float* hb    = (const float*)d_in[23];
  const float* e1w   = (const float*)d_in[24];
  const float* e1b   = (const float*)d_in[25];
  const float* e2w   = (const float*)d_in[26];
  const float* e2b   = (const float*)d_in[27];
  float* out = (float*)d_out;

  float* p     = (float*)d_ws;
  float* x     = p; p += BTCN;
  float* xg    = p; p += BTCNc;
  float* tmp1  = p; p += BTCNc;
  float* gout  = p; p += BTCNc;
  float* skipK = p; p += (size_t)Bb*Kk*Cc*Tt;
  float* adp   = p; p += (size_t)Nn*Nn;
  float* zT    = p; p += (size_t)1024*Nn;
  float* rT    = p; p += (size_t)1024*Nn;
  float* hxT   = p; p += (size_t)Nn*Nn;
  float* hhT   = p; p += (size_t)Nn*Nn;
  float* Xs    = p; p += (size_t)Tt*Bb*Nn;
  float* outs  = p; p += (size_t)Tt*Bb*Nn;
  float* h_g   = p; p += Bb*Nn;
  float* xin_g = p; p += Bb*Nn;
  float* rh_g  = p; p += Bb*Nn;
  int*   flags = (int*)p; p += Bb*GRU_P*32;

  k_wt<<<(Nn*1024 + 255)/256, 256, 0, stream>>>(zl, rl, hl, zT, rT, hxT, hhT);
  k_adp<<<Nn, 256, 0, stream>>>(nv1, nv2, adp);
  k_intransform<<<(int)((BTN + 255)/256), 256, 0, stream>>>(input, skw, skb, x);

  const float* sups[3] = {sup0, sup1, adp};
  for (int layer = 0; layer < Ll; layer++) {
    for (int chunk = 0; chunk < NCH; chunk++) {
      k_fgconv<<<(int)((BTNc + 255)/256), 256, 0, stream>>>(
          x, fw + layer*2048, fb + layer*32, gw + layer*2048, gb + layer*32,
          gcw + layer*32*224, gcb + layer*32, xg, gout, chunk);
      for (int s = 0; s < 3; s++) {
        k_supgemm<<<BTc*4, 256, 0, stream>>>(xg,   sups[s], gcw + layer*32*224, 2*s+1, tmp1, gout, 1);
        k_supgemm<<<BTc*4, 256, 0, stream>>>(tmp1, sups[s], gcw + layer*32*224, 2*s+2, tmp1, gout, 0);
      }
      k_skipgather<<<(BPC*Kk*Tt + 255)/256, 256, 0, stream>>>(xg, miss, skipK, chunk, layer == 0 ? 1 : 0);
      k_ingru<<<(int)((BTNc + 255)/256), 256, 0, stream>>>(gout, iw, ib2, Xs, chunk);
      k_xfold<<<(int)((BTCNc + 255)/256), 256, 0, stream>>>(x, gout, chunk);
    }
    hipMemsetAsync(flags, 0, Bb*GRU_P*32*sizeof(int), stream);
    k_gru4<<<dim3(Bb*GRU_P), dim3(512), 0, stream>>>(
        Xs, input, zT, rT, hxT, hhT, zb, rb, hb, h_g, xin_g, rh_g, outs, flags);
    k_xre<<<(int)((BTCN + 255)/256), 256, 0, stream>>>(x, outs, rw, rb2);
  }
  k_head<<<(Bb*Kk*Tt + 255)/256, 256, 0, stream>>>(skipK, e1w, e1b, e2w, e2b, out);
}

// Round 6
// 27999.554 us; speedup vs baseline: 1.6748x; 1.6748x over previous
//
#include <hip/hip_runtime.h>
#include <math.h>

#define Bb 8
#define Tt 168
#define Nn 512
#define Cc 32
#define Ll 4
#define Kk 50
#define NCH 4
#define BPC 2                     // batches per chunk (chunk boundary = t==0, no cross-chunk reads)
#define BTc (BPC*Tt)              // 336
#define BTNc ((size_t)BTc*Nn)
#define BTCNc ((size_t)BTc*Cc*Nn)
#define BT (Bb*Tt)
#define BTN ((size_t)Bb*Tt*Nn)
#define BTCN ((size_t)Bb*Tt*Cc*Nn)
#define GRUB 64                   // GRU blocks: each owns 8 output cols, all batches

__device__ __forceinline__ float sigm(float v) { return 1.0f/(1.0f + expf(-v)); }

__device__ __forceinline__ float sysload(const float* p) {
  return __hip_atomic_load(p, __ATOMIC_RELAXED, __HIP_MEMORY_SCOPE_SYSTEM);
}
__device__ __forceinline__ void sysstore(float* p, float v) {
  __hip_atomic_store(p, v, __ATOMIC_RELAXED, __HIP_MEMORY_SCOPE_SYSTEM);
}
__device__ __forceinline__ int flagload(const int* p) {
  return __hip_atomic_load(p, __ATOMIC_RELAXED, __HIP_MEMORY_SCOPE_SYSTEM);
}
__device__ __forceinline__ void flagstore(int* p, int v) {
  __hip_atomic_store(p, v, __ATOMIC_RELAXED, __HIP_MEMORY_SCOPE_SYSTEM);
}

// ---------------- pack GRU weights block-sliced: wpack[sl][c][kk], kk over [z|r|hx|hh] ----------------
__global__ void k_wt2(const float* __restrict__ zl, const float* __restrict__ rl,
                      const float* __restrict__ hl, float* __restrict__ wpack) {
  int idx = blockIdx.x*256 + threadIdx.x;       // 64*8*3072 = 1572864
  if (idx >= GRUB*8*3072) return;
  int kk = idx % 3072;
  int c  = (idx / 3072) & 7;
  int sl = idx / (3072*8);
  int ncol = sl*8 + c;
  float v;
  if (kk < 1024)      v = zl[ncol*1024 + kk];
  else if (kk < 2048) v = rl[ncol*1024 + (kk-1024)];
  else if (kk < 2560) v = hl[ncol*1024 + (kk-2048)];
  else                v = hl[ncol*1024 + 512 + (kk-2560)];
  wpack[idx] = v;
}

// ---------------- adaptive adjacency: softmax(relu(nv1@nv2), axis=1) ----------------
__global__ void k_adp(const float* __restrict__ nv1, const float* __restrict__ nv2,
                      float* __restrict__ adp) {
  int i = blockIdx.x;
  __shared__ float row[512];
  __shared__ float red[256];
  float v1[10];
  #pragma unroll
  for (int k=0;k<10;k++) v1[k] = nv1[i*10+k];
  for (int jj = threadIdx.x; jj < 512; jj += 256) {
    float s = 0.f;
    #pragma unroll
    for (int k=0;k<10;k++) s += v1[k]*nv2[k*Nn + jj];
    row[jj] = fmaxf(s, 0.f);
  }
  __syncthreads();
  float m = fmaxf(row[threadIdx.x], row[threadIdx.x+256]);
  red[threadIdx.x] = m; __syncthreads();
  for (int s=128; s>0; s>>=1) { if (threadIdx.x < s) red[threadIdx.x] = fmaxf(red[threadIdx.x], red[threadIdx.x+s]); __syncthreads(); }
  float mx = red[0]; __syncthreads();
  float e0 = expf(row[threadIdx.x]      - mx);
  float e1 = expf(row[threadIdx.x+256]  - mx);
  red[threadIdx.x] = e0 + e1; __syncthreads();
  for (int s=128; s>0; s>>=1) { if (threadIdx.x < s) red[threadIdx.x] += red[threadIdx.x+s]; __syncthreads(); }
  float inv = 1.f/red[0];
  adp[(size_t)i*Nn + threadIdx.x]       = e0*inv;
  adp[(size_t)i*Nn + threadIdx.x + 256] = e1*inv;
}

// ---------------- input transform: x = conv1x1(input[[0,3,5,6]]) -> (B,T,C,N) ----------------
__global__ void k_intransform(const float* __restrict__ input, const float* __restrict__ skw,
                              const float* __restrict__ skb, float* __restrict__ x) {
  size_t idx = (size_t)blockIdx.x*256 + threadIdx.x;
  if (idx >= BTN) return;
  int n = idx & 511;
  size_t bt = idx >> 9;
  int b = (int)(bt / Tt), t = (int)(bt % Tt);
  size_t chs = (size_t)Tt*Nn;
  size_t base = (((size_t)b*7)*Tt + t)*Nn + n;
  float v0 = input[base + 0*chs];
  float v3 = input[base + 3*chs];
  float v5 = input[base + 5*chs];
  float v6 = input[base + 6*chs];
  float* xp = x + bt*Cc*Nn + n;
  #pragma unroll
  for (int c=0;c<32;c++)
    xp[(size_t)c*Nn] = skb[c] + skw[c*4+0]*v0 + skw[c*4+1]*v3 + skw[c*4+2]*v5 + skw[c*4+3]*v6;
}

// ---------------- fused filter/gate conv1x2 -> xg_q ; gout_q = W0@xg + bias (chunk-local) ----------------
__launch_bounds__(256)
__global__ void k_fgconv(const float* __restrict__ x, const float* __restrict__ fw,
                         const float* __restrict__ fb, const float* __restrict__ gw,
                         const float* __restrict__ gb, const float* __restrict__ gcwl,
                         const float* __restrict__ gcb,
                         float* __restrict__ xg, float* __restrict__ gout, int chunk) {
  __shared__ float sfw[2048], sgw[2048], sw0[1024], sfb[32], sgb[32], sgcb[32];
  for (int l = threadIdx.x; l < 2048; l += 256) { sfw[l] = fw[l]; sgw[l] = gw[l]; }
  for (int l = threadIdx.x; l < 1024; l += 256) sw0[l] = gcwl[(l>>5)*224 + (l&31)];
  if (threadIdx.x < 32) {
    sfb[threadIdx.x] = fb[threadIdx.x];
    sgb[threadIdx.x] = gb[threadIdx.x];
    sgcb[threadIdx.x] = gcb[threadIdx.x];
  }
  __syncthreads();
  size_t idx = (size_t)blockIdx.x*256 + threadIdx.x;
  if (idx >= BTNc) return;
  int n = idx & 511;
  size_t btl = idx >> 9;
  int t = (int)(btl % Tt);
  size_t btg = (size_t)chunk*BTc + btl;
  const float* xp = x + btg*Cc*Nn + n;
  float xl[32], xr[32];
  #pragma unroll
  for (int c=0;c<32;c++) xr[c] = xp[(size_t)c*Nn];
  if (t == 0) {
    #pragma unroll
    for (int c=0;c<32;c++) xl[c] = 0.f;
  } else {
    const float* xq = xp - (size_t)Cc*Nn;
    #pragma unroll
    for (int c=0;c<32;c++) xl[c] = xq[(size_t)c*Nn];
  }
  float xgv[32];
  for (int c=0;c<32;c++) {
    float f = sfb[c], g = sgb[c];
    #pragma unroll
    for (int cp=0;cp<32;cp++) {
      f += xl[cp]*sfw[(c*32+cp)*2] + xr[cp]*sfw[(c*32+cp)*2+1];
      g += xl[cp]*sgw[(c*32+cp)*2] + xr[cp]*sgw[(c*32+cp)*2+1];
    }
    xgv[c] = tanhf(f) * sigm(g);
  }
  float* xgp = xg + btl*Cc*Nn + n;
  #pragma unroll
  for (int c=0;c<32;c++) xgp[(size_t)c*Nn] = xgv[c];
  float* gp = gout + btl*Cc*Nn + n;
  for (int o=0;o<32;o++) {
    float s = sgcb[o];
    #pragma unroll
    for (int c=0;c<32;c++) s += sw0[o*32+c]*xgv[c];
    gp[(size_t)o*Nn] = s;
  }
}

// ---------------- support GEMM (per bt: (32x512)@(512x512)) + gconv-slot epilogue ----------------
__launch_bounds__(256)
__global__ void k_supgemm(const float* __restrict__ X, const float* __restrict__ A,
                          const float* __restrict__ gcw, int pslot,
                          float* __restrict__ Y, float* __restrict__ gout, int storeY) {
  __shared__ float sX[32][33];
  __shared__ float sA[32][128];
  __shared__ float sW[1024];
  int tid = threadIdx.x;
  int bt = blockIdx.x >> 2;
  int n0 = (blockIdx.x & 3) << 7;
  const float* Xp = X + (size_t)bt*Cc*Nn;
  for (int l = tid; l < 1024; l += 256)
    sW[l] = gcw[(l>>5)*224 + pslot*32 + (l&31)];
  int tx = tid & 31, ty = tid >> 5;
  float acc[4][4];
  #pragma unroll
  for (int i=0;i<4;i++) { acc[i][0]=0.f; acc[i][1]=0.f; acc[i][2]=0.f; acc[i][3]=0.f; }
  for (int k0 = 0; k0 < Nn; k0 += 32) {
    {
      int r = tid >> 3, kk = (tid & 7) << 2;
      const float4 v = *reinterpret_cast<const float4*>(Xp + (size_t)r*Nn + k0 + kk);
      sX[r][kk] = v.x; sX[r][kk+1] = v.y; sX[r][kk+2] = v.z; sX[r][kk+3] = v.w;
    }
    #pragma unroll
    for (int i=0;i<4;i++) {
      int l = tid + i*256;
      int r = l >> 5, cg_ = l & 31;
      *reinterpret_cast<float4*>(&sA[r][cg_<<2]) =
        *reinterpret_cast<const float4*>(A + (size_t)(k0+r)*Nn + n0 + (cg_<<2));
    }
    __syncthreads();
    #pragma unroll
    for (int k=0;k<32;k++) {
      float4 bv = *reinterpret_cast<const float4*>(&sA[k][tx<<2]);
      float a0 = sX[(ty<<2)+0][k];
      float a1 = sX[(ty<<2)+1][k];
      float a2 = sX[(ty<<2)+2][k];
      float a3 = sX[(ty<<2)+3][k];
      acc[0][0]+=a0*bv.x; acc[0][1]+=a0*bv.y; acc[0][2]+=a0*bv.z; acc[0][3]+=a0*bv.w;
      acc[1][0]+=a1*bv.x; acc[1][1]+=a1*bv.y; acc[1][2]+=a1*bv.z; acc[1][3]+=a1*bv.w;
      acc[2][0]+=a2*bv.x; acc[2][1]+=a2*bv.y; acc[2][2]+=a2*bv.z; acc[2][3]+=a2*bv.w;
      acc[3][0]+=a3*bv.x; acc[3][1]+=a3*bv.y; acc[3][2]+=a3*bv.z; acc[3][3]+=a3*bv.w;
    }
    __syncthreads();
  }
  if (storeY) {
    float* Yp = Y + (size_t)bt*Cc*Nn + n0 + (tx<<2);
    #pragma unroll
    for (int i=0;i<4;i++)
      *reinterpret_cast<float4*>(Yp + (size_t)((ty<<2)+i)*Nn) =
        make_float4(acc[i][0],acc[i][1],acc[i][2],acc[i][3]);
  }
  #pragma unroll
  for (int i=0;i<4;i++)
    *reinterpret_cast<float4*>(&sA[(ty<<2)+i][tx<<2]) =
      make_float4(acc[i][0],acc[i][1],acc[i][2],acc[i][3]);
  __syncthreads();
  float og[4][4];
  #pragma unroll
  for (int i=0;i<4;i++) { og[i][0]=0.f; og[i][1]=0.f; og[i][2]=0.f; og[i][3]=0.f; }
  #pragma unroll 8
  for (int c=0;c<32;c++) {
    float4 yv = *reinterpret_cast<const float4*>(&sA[c][tx<<2]);
    float w0 = sW[((ty<<2)+0)*32 + c];
    float w1 = sW[((ty<<2)+1)*32 + c];
    float w2 = sW[((ty<<2)+2)*32 + c];
    float w3 = sW[((ty<<2)+3)*32 + c];
    og[0][0]+=w0*yv.x; og[0][1]+=w0*yv.y; og[0][2]+=w0*yv.z; og[0][3]+=w0*yv.w;
    og[1][0]+=w1*yv.x; og[1][1]+=w1*yv.y; og[1][2]+=w1*yv.z; og[1][3]+=w1*yv.w;
    og[2][0]+=w2*yv.x; og[2][1]+=w2*yv.y; og[2][2]+=w2*yv.z; og[2][3]+=w2*yv.w;
    og[3][0]+=w3*yv.x; og[3][1]+=w3*yv.y; og[3][2]+=w3*yv.z; og[3][3]+=w3*yv.w;
  }
  float* gp = gout + (size_t)bt*Cc*Nn + n0 + (tx<<2);
  #pragma unroll
  for (int i=0;i<4;i++) {
    float4 cur = *reinterpret_cast<float4*>(gp + (size_t)((ty<<2)+i)*Nn);
    cur.x += og[i][0]; cur.y += og[i][1]; cur.z += og[i][2]; cur.w += og[i][3];
    *reinterpret_cast<float4*>(gp + (size_t)((ty<<2)+i)*Nn) = cur;
  }
}

// ---------------- skip gather: skipK[b,k,c,t] (+)= xg_q[btl,c,node] ----------------
__global__ void k_skipgather(const float* __restrict__ xg, const int* __restrict__ miss,
                             float* __restrict__ skipK, int chunk, int first) {
  int idx = blockIdx.x*256 + threadIdx.x;
  if (idx >= BPC*Kk*Tt) return;
  int t = idx % Tt;
  int k = (idx / Tt) % Kk;
  int bloc = idx / (Tt*Kk);
  int bg = chunk*BPC + bloc;
  int node = miss[bg*Kk + k];
  const float* xp = xg + (((size_t)bloc*Tt + t)*Cc)*Nn + node;
  float* sp = skipK + (((size_t)bg*Kk + k)*Cc)*Tt + t;
  #pragma unroll
  for (int c=0;c<32;c++) {
    float v = xp[(size_t)c*Nn];
    sp[(size_t)c*Tt] = first ? v : (sp[(size_t)c*Tt] + v);
  }
}

// ---------------- ingru: Xs[t,b,n] = sum_c gout_q*iw + ib ----------------
__global__ void k_ingru(const float* __restrict__ gout, const float* __restrict__ iw,
                        const float* __restrict__ ib2, float* __restrict__ Xs, int chunk) {
  size_t idx = (size_t)blockIdx.x*256 + threadIdx.x;
  if (idx >= BTNc) return;
  int n = idx & 511;
  size_t btl = idx >> 9;
  int b = chunk*BPC + (int)(btl / Tt), t = (int)(btl % Tt);
  const float* gp = gout + btl*Cc*Nn + n;
  float s = ib2[0];
  #pragma unroll
  for (int c=0;c<Cc;c++) s += iw[c]*gp[(size_t)c*Nn];
  Xs[((size_t)t*Bb + b)*Nn + n] = s;
}

// ---------------- x += gout_q (chunk fold) ----------------
__global__ void k_xfold(float* __restrict__ x, const float* __restrict__ gout, int chunk) {
  size_t idx = (size_t)blockIdx.x*256 + threadIdx.x;
  if (idx >= BTCNc) return;
  x[(size_t)chunk*BTCNc + idx] += gout[idx];
}

// ---------------- GRU v5: 64 blocks, 8 cols x 8 batches each, WEIGHTS IN LDS ----------------
// Weights staged to LDS once (96KB/block) -> the t-loop never touches L2 for weights
// (round-5 diagnosis: per-step L2 weight re-reads were latency-bound at ~46us/step).
// Cross-block state (xin,h,rh: 48KB/step) via SYSTEM-scope bypass ops + flag barrier.
__launch_bounds__(512, 1)
__global__ void k_gru5(const float* __restrict__ Xs, const float* __restrict__ input,
                       const float* __restrict__ wpack,
                       const float* __restrict__ zb, const float* __restrict__ rb,
                       const float* __restrict__ hb,
                       float* __restrict__ h_g, float* __restrict__ xin_g,
                       float* __restrict__ rh_g, float* __restrict__ outs,
                       int* __restrict__ flags) {
  __shared__ float wl[8*3072];   // 96KB: [c][kk], kk: z(0:1024)|r(1024:2048)|hx(2048:2560)|hh(2560:3072)
  __shared__ float xh[8*1024];   // 32KB: [b][ xin(0:512) | h(512:1024) ]; xin half re-used for rh in phase B
  const int tid = threadIdx.x;
  const int sl  = blockIdx.x;       // col slice: owns n0..n0+7
  const int n0  = sl*8;
  const int b   = tid >> 6;         // wave = batch
  const int q   = tid & 63;         // 64-way K split
  int* myflag = flags + sl*32;

#define SIGNAL_WAIT(v) do { \
    asm volatile("s_waitcnt vmcnt(0)" ::: "memory"); \
    __syncthreads(); \
    if (tid == 0) flagstore(myflag, (v)); \
    if (tid < GRUB) { \
      const int* fl = flags + tid*32; \
      while (flagload(fl) < (v)) __builtin_amdgcn_s_sleep(1); \
    } \
    __syncthreads(); \
  } while (0)

  // stage weights once (coalesced float4 from packed buffer)
  {
    const float4* src = reinterpret_cast<const float4*>(wpack + (size_t)sl*24576);
    float4* dst = reinterpret_cast<float4*>(wl);
    #pragma unroll 4
    for (int i = tid; i < 6144; i += 512) dst[i] = src[i];
  }
  // t=0 init for own cols
  if (tid < 64) {
    int bb = tid >> 3, c = tid & 7, nn = n0 + c;
    float Xi = Xs[(size_t)bb*Nn + nn];
    float Mi = input[(((size_t)bb*7+1)*Tt + 0)*Nn + nn];
    sysstore(h_g + bb*Nn + nn, 0.f);
    sysstore(xin_g + bb*Nn + nn, sigm(Xi*Mi));
  }
  SIGNAL_WAIT(1);

  float zbv[8], rbv[8], hbv[8];
  #pragma unroll
  for (int c=0;c<8;c++) { zbv[c]=zb[n0+c]; rbv[c]=rb[n0+c]; hbv[c]=hb[n0+c]; }

  float zs[8], axs[8];
  float* xb = xh + b*1024;

  for (int t = 0; t < Tt; t++) {
    // ---- stage xin,h -> LDS (bypass loads, pipelined) ----
    #pragma unroll
    for (int i = 0; i < 16; i++) {
      int bb = i >> 1;
      float v = (i & 1) ? sysload(h_g + bb*Nn + tid) : sysload(xin_g + bb*Nn + tid);
      xh[i*512 + tid] = v;   // linear == [bb][ (i&1)*512 + tid ]
    }
    __syncthreads();
    // ---- phase A: z, r (K=1024), hx (K=512) from LDS ----
    float az[8], ar[8], ax[8];
    #pragma unroll
    for (int c=0;c<8;c++) { az[c]=0.f; ar[c]=0.f; ax[c]=0.f; }
    #pragma unroll 2
    for (int i = 0; i < 8; i++) {
      int k = i*128 + q*2;
      float2 xv = *reinterpret_cast<const float2*>(xb + k);
      #pragma unroll
      for (int c = 0; c < 8; c++) {
        float2 wz = *reinterpret_cast<const float2*>(wl + c*3072 + k);
        float2 wr = *reinterpret_cast<const float2*>(wl + c*3072 + 1024 + k);
        az[c] += xv.x*wz.x + xv.y*wz.y;
        ar[c] += xv.x*wr.x + xv.y*wr.y;
      }
    }
    #pragma unroll 2
    for (int i = 0; i < 4; i++) {
      int k = i*128 + q*2;
      float2 xv = *reinterpret_cast<const float2*>(xb + k);      // xin half
      #pragma unroll
      for (int c = 0; c < 8; c++) {
        float2 wx = *reinterpret_cast<const float2*>(wl + c*3072 + 2048 + k);
        ax[c] += xv.x*wx.x + xv.y*wx.y;
      }
    }
    #pragma unroll
    for (int d = 1; d < 64; d <<= 1) {
      #pragma unroll
      for (int c = 0; c < 8; c++) {
        az[c] += __shfl_xor(az[c], d);
        ar[c] += __shfl_xor(ar[c], d);
        ax[c] += __shfl_xor(ax[c], d);
      }
    }
    if (q == 0) {
      #pragma unroll
      for (int c = 0; c < 8; c++) {
        zs[c]  = sigm(az[c] + zbv[c]);
        axs[c] = ax[c];
        float r  = sigm(ar[c] + rbv[c]);
        float hv = xb[512 + n0 + c];
        sysstore(rh_g + b*Nn + n0 + c, r*hv);
      }
    }
    SIGNAL_WAIT(2 + 2*t);
    // ---- stage rh into xin half of xh (xin dead in phase B) ----
    #pragma unroll
    for (int i = 0; i < 8; i++) {
      int bb = i >> 0;   // 8 iterations cover 8*512
      float v = sysload(rh_g + i*Nn + tid);
      xh[i*1024 + tid] = v;      // [bb][0:512] slot
    }
    __syncthreads();
    // ---- phase B: hh (K=512) + combine ----
    float ah[8];
    #pragma unroll
    for (int c=0;c<8;c++) ah[c]=0.f;
    #pragma unroll 2
    for (int i = 0; i < 4; i++) {
      int k = i*128 + q*2;
      float2 rv = *reinterpret_cast<const float2*>(xb + k);      // rh staged here
      #pragma unroll
      for (int c = 0; c < 8; c++) {
        float2 wh = *reinterpret_cast<const float2*>(wl + c*3072 + 2560 + k);
        ah[c] += rv.x*wh.x + rv.y*wh.y;
      }
    }
    #pragma unroll
    for (int d = 1; d < 64; d <<= 1) {
      #pragma unroll
      for (int c = 0; c < 8; c++) ah[c] += __shfl_xor(ah[c], d);
    }
    if (q == 0) {
      #pragma unroll
      for (int c = 0; c < 8; c++) {
        float hv = xb[512 + n0 + c];
        float ht = tanhf(axs[c] + ah[c] + hbv[c]);
        float hn = (1.f - zs[c])*hv + zs[c]*ht;
        outs[((size_t)t*Bb + b)*Nn + n0 + c] = hn;
        sysstore(h_g + b*Nn + n0 + c, hn);
        if (t+1 < Tt) {
          float Xi = Xs[((size_t)(t+1)*Bb + b)*Nn + n0 + c];
          float Mi = input[(((size_t)b*7+1)*Tt + (t+1))*Nn + n0 + c];
          sysstore(xin_g + b*Nn + n0 + c, sigm(Xi*Mi + hn*(1.f - Mi)));
        }
      }
    }
    SIGNAL_WAIT(3 + 2*t);
  }
#undef SIGNAL_WAIT
}

// ---------------- x += outs*rw + rb (after GRU) ----------------
__global__ void k_xre(float* __restrict__ x, const float* __restrict__ outs,
                      const float* __restrict__ rw, const float* __restrict__ rb2) {
  size_t idx = (size_t)blockIdx.x*256 + threadIdx.x;
  if (idx >= BTCN) return;
  int n = idx & 511;
  int c = (int)((idx >> 9) & 31);
  size_t bt = idx >> 14;
  int b = (int)(bt / Tt), t = (int)(bt % Tt);
  float o = outs[((size_t)t*Bb + b)*Nn + n];
  x[idx] += o*rw[c] + rb2[c];
}

// ---------------- head: relu(skipK) -> end1 relu -> end2 ----------------
__launch_bounds__(256)
__global__ void k_head(const float* __restrict__ skipK,
                       const float* __restrict__ e1w, const float* __restrict__ e1b,
                       const float* __restrict__ e2w, const float* __restrict__ e2b,
                       float* __restrict__ out) {
  __shared__ float sw[2048], sb[64], s2[64];
  for (int l = threadIdx.x; l < 2048; l += 256) sw[l] = e1w[l];
  if (threadIdx.x < 64) { sb[threadIdx.x] = e1b[threadIdx.x]; s2[threadIdx.x] = e2w[threadIdx.x]; }
  __syncthreads();
  int idx = blockIdx.x*256 + threadIdx.x;
  if (idx >= Bb*Kk*Tt) return;
  int t = idx % Tt;
  int k = (idx / Tt) % Kk;
  int b = idx / (Tt*Kk);
  const float* sp = skipK + (((size_t)b*Kk + k)*Cc)*Tt + t;
  float in[32];
  #pragma unroll
  for (int c=0;c<32;c++) in[c] = fmaxf(sp[(size_t)c*Tt], 0.f);
  float acc = e2b[0];
  for (int o=0;o<64;o++) {
    float s = sb[o];
    #pragma unroll
    for (int c=0;c<32;c++) s += sw[o*32+c]*in[c];
    acc += s2[o]*fmaxf(s, 0.f);
  }
  out[idx] = acc;
}

extern "C" void kernel_launch(void* const* d_in, const int* in_sizes, int n_in,
                              void* d_out, int out_size, void* d_ws, size_t ws_size,
                              hipStream_t stream) {
  const float* input = (const float*)d_in[0];
  const int*   miss  = (const int*)  d_in[1];
  const float* sup0  = (const float*)d_in[2];
  const float* sup1  = (const float*)d_in[3];
  const float* nv1   = (const float*)d_in[4];
  const float* nv2   = (const float*)d_in[5];
  const float* skw   = (const float*)d_in[6];
  const float* skb   = (const float*)d_in[7];
  const float* fw    = (const float*)d_in[8];
  const float* fb    = (const float*)d_in[9];
  const float* gw    = (const float*)d_in[10];
  const float* gb    = (const float*)d_in[11];
  const float* gcw   = (const float*)d_in[12];
  const float* gcb   = (const float*)d_in[13];
  const float* iw    = (const float*)d_in[14];
  const float* ib2   = (const float*)d_in[15];
  const float* rw    = (const float*)d_in[16];
  const float* rb2   = (const float*)d_in[17];
  const float* zl    = (const float*)d_in[18];
  const float* zb    = (const float*)d_in[19];
  const float* rl    = (const float*)d_in[20];
  const float* rb    = (const float*)d_in[21];
  const float* hl    = (const float*)d_in[22];
  const float* hb    = (const float*)d_in[23];
  const float* e1w   = (const float*)d_in[24];
  const float* e1b   = (const float*)d_in[25];
  const float* e2w   = (const float*)d_in[26];
  const float* e2b   = (const float*)d_in[27];
  float* out = (float*)d_out;

  float* p     = (float*)d_ws;
  float* x     = p; p += BTCN;
  float* xg    = p; p += BTCNc;
  float* tmp1  = p; p += BTCNc;
  float* gout  = p; p += BTCNc;
  float* skipK = p; p += (size_t)Bb*Kk*Cc*Tt;
  float* adp   = p; p += (size_t)Nn*Nn;
  float* wpack = p; p += (size_t)GRUB*8*3072;     // 6MB packed GRU weights
  float* Xs    = p; p += (size_t)Tt*Bb*Nn;
  float* outs  = p; p += (size_t)Tt*Bb*Nn;
  float* h_g   = p; p += Bb*Nn;
  float* xin_g = p; p += Bb*Nn;
  float* rh_g  = p; p += Bb*Nn;
  int*   flags = (int*)p; p += GRUB*32;

  k_wt2<<<(GRUB*8*3072 + 255)/256, 256, 0, stream>>>(zl, rl, hl, wpack);
  k_adp<<<Nn, 256, 0, stream>>>(nv1, nv2, adp);
  k_intransform<<<(int)((BTN + 255)/256), 256, 0, stream>>>(input, skw, skb, x);

  const float* sups[3] = {sup0, sup1, adp};
  for (int layer = 0; layer < Ll; layer++) {
    for (int chunk = 0; chunk < NCH; chunk++) {
      k_fgconv<<<(int)((BTNc + 255)/256), 256, 0, stream>>>(
          x, fw + layer*2048, fb + layer*32, gw + layer*2048, gb + layer*32,
          gcw + layer*32*224, gcb + layer*32, xg, gout, chunk);
      for (int s = 0; s < 3; s++) {
        k_supgemm<<<BTc*4, 256, 0, stream>>>(xg,   sups[s], gcw + layer*32*224, 2*s+1, tmp1, gout, 1);
        k_supgemm<<<BTc*4, 256, 0, stream>>>(tmp1, sups[s], gcw + layer*32*224, 2*s+2, tmp1, gout, 0);
      }
      k_skipgather<<<(BPC*Kk*Tt + 255)/256, 256, 0, stream>>>(xg, miss, skipK, chunk, layer == 0 ? 1 : 0);
      k_ingru<<<(int)((BTNc + 255)/256), 256, 0, stream>>>(gout, iw, ib2, Xs, chunk);
      k_xfold<<<(int)((BTCNc + 255)/256), 256, 0, stream>>>(x, gout, chunk);
    }
    hipMemsetAsync(flags, 0, GRUB*32*sizeof(int), stream);
    k_gru5<<<dim3(GRUB), dim3(512), 0, stream>>>(
        Xs, input, wpack, zb, rb, hb, h_g, xin_g, rh_g, outs, flags);
    k_xre<<<(int)((BTCN + 255)/256), 256, 0, stream>>>(x, outs, rw, rb2);
  }
  k_head<<<(Bb*Kk*Tt + 255)/256, 256, 0, stream>>>(skipK, e1w, e1b, e2w, e2b, out);
}

// Round 7
// 21185.074 us; speedup vs baseline: 2.2135x; 1.3217x over previous
//
#include <hip/hip_runtime.h>
#include <math.h>

#define Bb 8
#define Tt 168
#define Nn 512
#define Cc 32
#define Ll 4
#define Kk 50
#define NCH 4
#define BPC 2                     // batches per chunk (chunk boundary = t==0, no cross-chunk reads)
#define BTc (BPC*Tt)              // 336
#define BTNc ((size_t)BTc*Nn)
#define BTCNc ((size_t)BTc*Cc*Nn)
#define BT (Bb*Tt)
#define BTN ((size_t)Bb*Tt*Nn)
#define BTCN ((size_t)Bb*Tt*Cc*Nn)
#define GRUB 64                   // GRU blocks: each owns 8 output cols, all batches

typedef __attribute__((ext_vector_type(8))) short short8v;
typedef __attribute__((ext_vector_type(4))) float f32x4;

__device__ __forceinline__ float sigm(float v) { return 1.0f/(1.0f + expf(-v)); }

__device__ __forceinline__ unsigned int f2bf(float x) {   // RNE, returns bits in low 16
  unsigned int u = __float_as_uint(x);
  u = u + 0x7FFFu + ((u >> 16) & 1u);
  return u >> 16;
}
__device__ __forceinline__ float bf2f(unsigned int h) {
  return __uint_as_float(h << 16);
}

__device__ __forceinline__ float sysload(const float* p) {
  return __hip_atomic_load(p, __ATOMIC_RELAXED, __HIP_MEMORY_SCOPE_SYSTEM);
}
__device__ __forceinline__ void sysstore(float* p, float v) {
  __hip_atomic_store(p, v, __ATOMIC_RELAXED, __HIP_MEMORY_SCOPE_SYSTEM);
}
__device__ __forceinline__ int flagload(const int* p) {
  return __hip_atomic_load(p, __ATOMIC_RELAXED, __HIP_MEMORY_SCOPE_SYSTEM);
}
__device__ __forceinline__ void flagstore(int* p, int v) {
  __hip_atomic_store(p, v, __ATOMIC_RELAXED, __HIP_MEMORY_SCOPE_SYSTEM);
}

// ---------------- pack GRU weights block-sliced: wpack[sl][c][kk], kk over [z|r|hx|hh] ----------------
__global__ void k_wt2(const float* __restrict__ zl, const float* __restrict__ rl,
                      const float* __restrict__ hl, float* __restrict__ wpack) {
  int idx = blockIdx.x*256 + threadIdx.x;       // 64*8*3072 = 1572864
  if (idx >= GRUB*8*3072) return;
  int kk = idx % 3072;
  int c  = (idx / 3072) & 7;
  int sl = idx / (3072*8);
  int ncol = sl*8 + c;
  float v;
  if (kk < 1024)      v = zl[ncol*1024 + kk];
  else if (kk < 2048) v = rl[ncol*1024 + (kk-1024)];
  else if (kk < 2560) v = hl[ncol*1024 + (kk-2048)];
  else                v = hl[ncol*1024 + 512 + (kk-2560)];
  wpack[idx] = v;
}

// ---------------- adaptive adjacency: softmax(relu(nv1@nv2), axis=1) ----------------
__global__ void k_adp(const float* __restrict__ nv1, const float* __restrict__ nv2,
                      float* __restrict__ adp) {
  int i = blockIdx.x;
  __shared__ float row[512];
  __shared__ float red[256];
  float v1[10];
  #pragma unroll
  for (int k=0;k<10;k++) v1[k] = nv1[i*10+k];
  for (int jj = threadIdx.x; jj < 512; jj += 256) {
    float s = 0.f;
    #pragma unroll
    for (int k=0;k<10;k++) s += v1[k]*nv2[k*Nn + jj];
    row[jj] = fmaxf(s, 0.f);
  }
  __syncthreads();
  float m = fmaxf(row[threadIdx.x], row[threadIdx.x+256]);
  red[threadIdx.x] = m; __syncthreads();
  for (int s=128; s>0; s>>=1) { if (threadIdx.x < s) red[threadIdx.x] = fmaxf(red[threadIdx.x], red[threadIdx.x+s]); __syncthreads(); }
  float mx = red[0]; __syncthreads();
  float e0 = expf(row[threadIdx.x]      - mx);
  float e1 = expf(row[threadIdx.x+256]  - mx);
  red[threadIdx.x] = e0 + e1; __syncthreads();
  for (int s=128; s>0; s>>=1) { if (threadIdx.x < s) red[threadIdx.x] += red[threadIdx.x+s]; __syncthreads(); }
  float inv = 1.f/red[0];
  adp[(size_t)i*Nn + threadIdx.x]       = e0*inv;
  adp[(size_t)i*Nn + threadIdx.x + 256] = e1*inv;
}

// ---------------- split supports to transposed bf16 hi/lo: ShiT[s][n][k] ----------------
__global__ void k_sprep(const float* __restrict__ sup0, const float* __restrict__ sup1,
                        const float* __restrict__ adp,
                        unsigned short* __restrict__ ShiT, unsigned short* __restrict__ SloT) {
  int idx = blockIdx.x*256 + threadIdx.x;
  if (idx >= 3*512*512) return;
  int s = idx >> 18;
  int rem = idx & 262143;
  int n = rem >> 9, k = rem & 511;
  const float* S = (s==0) ? sup0 : (s==1) ? sup1 : adp;
  float v = S[k*512 + n];
  unsigned int h = f2bf(v);
  float lo = v - bf2f(h);
  ShiT[idx] = (unsigned short)h;
  SloT[idx] = (unsigned short)f2bf(lo);
}

// ---------------- input transform: x = conv1x1(input[[0,3,5,6]]) -> (B,T,C,N) ----------------
__global__ void k_intransform(const float* __restrict__ input, const float* __restrict__ skw,
                              const float* __restrict__ skb, float* __restrict__ x) {
  size_t idx = (size_t)blockIdx.x*256 + threadIdx.x;
  if (idx >= BTN) return;
  int n = idx & 511;
  size_t bt = idx >> 9;
  int b = (int)(bt / Tt), t = (int)(bt % Tt);
  size_t chs = (size_t)Tt*Nn;
  size_t base = (((size_t)b*7)*Tt + t)*Nn + n;
  float v0 = input[base + 0*chs];
  float v3 = input[base + 3*chs];
  float v5 = input[base + 5*chs];
  float v6 = input[base + 6*chs];
  float* xp = x + bt*Cc*Nn + n;
  #pragma unroll
  for (int c=0;c<32;c++)
    xp[(size_t)c*Nn] = skb[c] + skw[c*4+0]*v0 + skw[c*4+1]*v3 + skw[c*4+2]*v5 + skw[c*4+3]*v6;
}

// ---------------- fused filter/gate conv1x2 -> xg_q ; gout_q = W0@xg + bias (chunk-local) ----------------
__launch_bounds__(256)
__global__ void k_fgconv(const float* __restrict__ x, const float* __restrict__ fw,
                         const float* __restrict__ fb, const float* __restrict__ gw,
                         const float* __restrict__ gb, const float* __restrict__ gcwl,
                         const float* __restrict__ gcb,
                         float* __restrict__ xg, float* __restrict__ gout, int chunk) {
  __shared__ float sfw[2048], sgw[2048], sw0[1024], sfb[32], sgb[32], sgcb[32];
  for (int l = threadIdx.x; l < 2048; l += 256) { sfw[l] = fw[l]; sgw[l] = gw[l]; }
  for (int l = threadIdx.x; l < 1024; l += 256) sw0[l] = gcwl[(l>>5)*224 + (l&31)];
  if (threadIdx.x < 32) {
    sfb[threadIdx.x] = fb[threadIdx.x];
    sgb[threadIdx.x] = gb[threadIdx.x];
    sgcb[threadIdx.x] = gcb[threadIdx.x];
  }
  __syncthreads();
  size_t idx = (size_t)blockIdx.x*256 + threadIdx.x;
  if (idx >= BTNc) return;
  int n = idx & 511;
  size_t btl = idx >> 9;
  int t = (int)(btl % Tt);
  size_t btg = (size_t)chunk*BTc + btl;
  const float* xp = x + btg*Cc*Nn + n;
  float xl[32], xr[32];
  #pragma unroll
  for (int c=0;c<32;c++) xr[c] = xp[(size_t)c*Nn];
  if (t == 0) {
    #pragma unroll
    for (int c=0;c<32;c++) xl[c] = 0.f;
  } else {
    const float* xq = xp - (size_t)Cc*Nn;
    #pragma unroll
    for (int c=0;c<32;c++) xl[c] = xq[(size_t)c*Nn];
  }
  float xgv[32];
  for (int c=0;c<32;c++) {
    float f = sfb[c], g = sgb[c];
    #pragma unroll
    for (int cp=0;cp<32;cp++) {
      f += xl[cp]*sfw[(c*32+cp)*2] + xr[cp]*sfw[(c*32+cp)*2+1];
      g += xl[cp]*sgw[(c*32+cp)*2] + xr[cp]*sgw[(c*32+cp)*2+1];
    }
    xgv[c] = tanhf(f) * sigm(g);
  }
  float* xgp = xg + btl*Cc*Nn + n;
  #pragma unroll
  for (int c=0;c<32;c++) xgp[(size_t)c*Nn] = xgv[c];
  float* gp = gout + btl*Cc*Nn + n;
  for (int o=0;o<32;o++) {
    float s = sgcb[o];
    #pragma unroll
    for (int c=0;c<32;c++) s += sw0[o*32+c]*xgv[c];
    gp[(size_t)o*Nn] = s;
  }
}

// ---------------- support GEMM via split-bf16 MFMA ----------------
// Block tile: M=64 (2 bt), N=128, K=512. 4 waves, each 64x32 out.
// Y = X @ S with X = Xhi+Xlo, S = Shi+Slo (bf16 RNE splits); 3 MFMA per product tile.
// Epilogue: optional fp32 Y store + gout[o][n] += sum_c W[o][c] Y[c][n].
__launch_bounds__(256)
__global__ void k_supmfma(const float* __restrict__ X,
                          const unsigned short* __restrict__ ShiT,
                          const unsigned short* __restrict__ SloT,
                          const float* __restrict__ gcw, int pslot,
                          float* __restrict__ Y, float* __restrict__ gout, int storeY) {
  __shared__ unsigned char smem[64*132*4];      // pool: staging (30720B) then sY (33792B)
  __shared__ float sW[1024];
  unsigned short* sXhi = (unsigned short*)smem;                 // 64*40
  unsigned short* sXlo = sXhi + 2560;
  unsigned short* sShi = sXlo + 2560;                           // 128*40
  unsigned short* sSlo = sShi + 5120;
  float* sY = (float*)smem;                                     // 64*132 (after K loop)
#define MW 40

  const int tid  = threadIdx.x;
  const int bt2  = blockIdx.x >> 2;
  const int colg = blockIdx.x & 3;
  const int bt0  = bt2*2;
  const int n0   = colg*128;
  const int lane = tid & 63, wv = tid >> 6;
  const int kb   = (lane >> 4)*8;

  for (int l = tid; l < 1024; l += 256)
    sW[l] = gcw[(l>>5)*224 + pslot*32 + (l&31)];

  f32x4 acc[4][2];
  #pragma unroll
  for (int i=0;i<4;i++) {
    #pragma unroll
    for (int j=0;j<2;j++) { acc[i][j].x=0.f; acc[i][j].y=0.f; acc[i][j].z=0.f; acc[i][j].w=0.f; }
  }

  const int sm  = tid >> 2;              // X stage: row 0..63
  const int skp = (tid & 3)*8;           // k part
  const size_t xrow = ((size_t)(bt0 + (sm>>5))*Cc + (sm&31))*Nn;
  const int sn  = tid >> 1;              // S stage: col-row 0..127
  const int shp = (tid & 1)*16;          // 16-k half

  for (int kc = 0; kc < 16; kc++) {
    const int k0 = kc*32;
    // ---- stage X chunk: fp32 -> bf16 hi/lo ----
    {
      float4 a0 = *reinterpret_cast<const float4*>(&X[xrow + k0 + skp]);
      float4 a1 = *reinterpret_cast<const float4*>(&X[xrow + k0 + skp + 4]);
      float v[8] = {a0.x,a0.y,a0.z,a0.w,a1.x,a1.y,a1.z,a1.w};
      unsigned int h[8], l[8];
      #pragma unroll
      for (int i=0;i<8;i++) {
        h[i] = f2bf(v[i]);
        l[i] = f2bf(v[i] - bf2f(h[i]));
      }
      uint4 H = { h[0]|(h[1]<<16), h[2]|(h[3]<<16), h[4]|(h[5]<<16), h[6]|(h[7]<<16) };
      uint4 L = { l[0]|(l[1]<<16), l[2]|(l[3]<<16), l[4]|(l[5]<<16), l[6]|(l[7]<<16) };
      *reinterpret_cast<uint4*>(&sXhi[sm*MW + skp]) = H;
      *reinterpret_cast<uint4*>(&sXlo[sm*MW + skp]) = L;
    }
    // ---- stage S^T chunk (pre-split bf16) ----
    {
      const size_t srow = (size_t)(n0 + sn)*512 + k0 + shp;
      *reinterpret_cast<uint4*>(&sShi[sn*MW + shp])     = *reinterpret_cast<const uint4*>(&ShiT[srow]);
      *reinterpret_cast<uint4*>(&sShi[sn*MW + shp + 8]) = *reinterpret_cast<const uint4*>(&ShiT[srow + 8]);
      *reinterpret_cast<uint4*>(&sSlo[sn*MW + shp])     = *reinterpret_cast<const uint4*>(&SloT[srow]);
      *reinterpret_cast<uint4*>(&sSlo[sn*MW + shp + 8]) = *reinterpret_cast<const uint4*>(&SloT[srow + 8]);
    }
    __syncthreads();
    // ---- fragments + MFMA ----
    short8v bhi[2], blo[2];
    #pragma unroll
    for (int ct=0; ct<2; ct++) {
      int col = wv*32 + ct*16 + (lane & 15);
      bhi[ct] = *reinterpret_cast<const short8v*>(&sShi[col*MW + kb]);
      blo[ct] = *reinterpret_cast<const short8v*>(&sSlo[col*MW + kb]);
    }
    #pragma unroll
    for (int rt=0; rt<4; rt++) {
      int row = rt*16 + (lane & 15);
      short8v ahi = *reinterpret_cast<const short8v*>(&sXhi[row*MW + kb]);
      short8v alo = *reinterpret_cast<const short8v*>(&sXlo[row*MW + kb]);
      #pragma unroll
      for (int ct=0; ct<2; ct++) {
        acc[rt][ct] = __builtin_amdgcn_mfma_f32_16x16x32_bf16(ahi, bhi[ct], acc[rt][ct], 0, 0, 0);
        acc[rt][ct] = __builtin_amdgcn_mfma_f32_16x16x32_bf16(ahi, blo[ct], acc[rt][ct], 0, 0, 0);
        acc[rt][ct] = __builtin_amdgcn_mfma_f32_16x16x32_bf16(alo, bhi[ct], acc[rt][ct], 0, 0, 0);
      }
    }
    __syncthreads();
  }
  // ---- acc -> sY (C/D layout: col=lane&15, row=(lane>>4)*4+reg) ----
  #pragma unroll
  for (int rt=0; rt<4; rt++) {
    #pragma unroll
    for (int ct=0; ct<2; ct++) {
      int col = wv*32 + ct*16 + (lane & 15);
      int rbase = rt*16 + (lane >> 4)*4;
      sY[(rbase+0)*132 + col] = acc[rt][ct].x;
      sY[(rbase+1)*132 + col] = acc[rt][ct].y;
      sY[(rbase+2)*132 + col] = acc[rt][ct].z;
      sY[(rbase+3)*132 + col] = acc[rt][ct].w;
    }
  }
  __syncthreads();
  // ---- optional Y store (fp32, feeds the chained GEMM) ----
  if (storeY) {
    for (int e = tid; e < 2048; e += 256) {
      int m = e >> 5, c4 = (e & 31)*4;
      float4 v = *reinterpret_cast<const float4*>(&sY[m*132 + c4]);
      *reinterpret_cast<float4*>(&Y[((size_t)(bt0 + (m>>5))*Cc + (m&31))*Nn + n0 + c4]) = v;
    }
  }
  // ---- W-mix epilogue -> gout ----
  {
    int tx = tid & 31, ty = tid >> 5;
    for (int btl = 0; btl < 2; btl++) {
      float og[4][4];
      #pragma unroll
      for (int i=0;i<4;i++) { og[i][0]=0.f; og[i][1]=0.f; og[i][2]=0.f; og[i][3]=0.f; }
      #pragma unroll 8
      for (int c = 0; c < 32; c++) {
        float4 yv = *reinterpret_cast<const float4*>(&sY[(btl*32 + c)*132 + tx*4]);
        float w0 = sW[((ty<<2)+0)*32 + c];
        float w1 = sW[((ty<<2)+1)*32 + c];
        float w2 = sW[((ty<<2)+2)*32 + c];
        float w3 = sW[((ty<<2)+3)*32 + c];
        og[0][0]+=w0*yv.x; og[0][1]+=w0*yv.y; og[0][2]+=w0*yv.z; og[0][3]+=w0*yv.w;
        og[1][0]+=w1*yv.x; og[1][1]+=w1*yv.y; og[1][2]+=w1*yv.z; og[1][3]+=w1*yv.w;
        og[2][0]+=w2*yv.x; og[2][1]+=w2*yv.y; og[2][2]+=w2*yv.z; og[2][3]+=w2*yv.w;
        og[3][0]+=w3*yv.x; og[3][1]+=w3*yv.y; og[3][2]+=w3*yv.z; og[3][3]+=w3*yv.w;
      }
      float* gp = gout + (size_t)(bt0+btl)*Cc*Nn + n0 + (tx<<2);
      #pragma unroll
      for (int i=0;i<4;i++) {
        float4 cur = *reinterpret_cast<float4*>(gp + (size_t)((ty<<2)+i)*Nn);
        cur.x += og[i][0]; cur.y += og[i][1]; cur.z += og[i][2]; cur.w += og[i][3];
        *reinterpret_cast<float4*>(gp + (size_t)((ty<<2)+i)*Nn) = cur;
      }
    }
  }
#undef MW
}

// ---------------- skip gather: skipK[b,k,c,t] (+)= xg_q[btl,c,node] ----------------
__global__ void k_skipgather(const float* __restrict__ xg, const int* __restrict__ miss,
                             float* __restrict__ skipK, int chunk, int first) {
  int idx = blockIdx.x*256 + threadIdx.x;
  if (idx >= BPC*Kk*Tt) return;
  int t = idx % Tt;
  int k = (idx / Tt) % Kk;
  int bloc = idx / (Tt*Kk);
  int bg = chunk*BPC + bloc;
  int node = miss[bg*Kk + k];
  const float* xp = xg + (((size_t)bloc*Tt + t)*Cc)*Nn + node;
  float* sp = skipK + (((size_t)bg*Kk + k)*Cc)*Tt + t;
  #pragma unroll
  for (int c=0;c<32;c++) {
    float v = xp[(size_t)c*Nn];
    sp[(size_t)c*Tt] = first ? v : (sp[(size_t)c*Tt] + v);
  }
}

// ---------------- ingru: Xs[t,b,n] = sum_c gout_q*iw + ib ----------------
__global__ void k_ingru(const float* __restrict__ gout, const float* __restrict__ iw,
                        const float* __restrict__ ib2, float* __restrict__ Xs, int chunk) {
  size_t idx = (size_t)blockIdx.x*256 + threadIdx.x;
  if (idx >= BTNc) return;
  int n = idx & 511;
  size_t btl = idx >> 9;
  int b = chunk*BPC + (int)(btl / Tt), t = (int)(btl % Tt);
  const float* gp = gout + btl*Cc*Nn + n;
  float s = ib2[0];
  #pragma unroll
  for (int c=0;c<Cc;c++) s += iw[c]*gp[(size_t)c*Nn];
  Xs[((size_t)t*Bb + b)*Nn + n] = s;
}

// ---------------- x += gout_q (chunk fold) ----------------
__global__ void k_xfold(float* __restrict__ x, const float* __restrict__ gout, int chunk) {
  size_t idx = (size_t)blockIdx.x*256 + threadIdx.x;
  if (idx >= BTCNc) return;
  x[(size_t)chunk*BTCNc + idx] += gout[idx];
}

// ---------------- GRU v5: 64 blocks, 8 cols x 8 batches each, WEIGHTS IN LDS ----------------
__launch_bounds__(512, 1)
__global__ void k_gru5(const float* __restrict__ Xs, const float* __restrict__ input,
                       const float* __restrict__ wpack,
                       const float* __restrict__ zb, const float* __restrict__ rb,
                       const float* __restrict__ hb,
                       float* __restrict__ h_g, float* __restrict__ xin_g,
                       float* __restrict__ rh_g, float* __restrict__ outs,
                       int* __restrict__ flags) {
  __shared__ float wl[8*3072];   // 96KB: [c][kk], kk: z(0:1024)|r(1024:2048)|hx(2048:2560)|hh(2560:3072)
  __shared__ float xh[8*1024];   // 32KB: [b][ xin(0:512) | h(512:1024) ]; xin half reused for rh
  const int tid = threadIdx.x;
  const int sl  = blockIdx.x;
  const int n0  = sl*8;
  const int b   = tid >> 6;
  const int q   = tid & 63;
  int* myflag = flags + sl*32;

#define SIGNAL_WAIT(v) do { \
    asm volatile("s_waitcnt vmcnt(0)" ::: "memory"); \
    __syncthreads(); \
    if (tid == 0) flagstore(myflag, (v)); \
    if (tid < GRUB) { \
      const int* fl = flags + tid*32; \
      while (flagload(fl) < (v)) __builtin_amdgcn_s_sleep(1); \
    } \
    __syncthreads(); \
  } while (0)

  {
    const float4* src = reinterpret_cast<const float4*>(wpack + (size_t)sl*24576);
    float4* dst = reinterpret_cast<float4*>(wl);
    #pragma unroll 4
    for (int i = tid; i < 6144; i += 512) dst[i] = src[i];
  }
  if (tid < 64) {
    int bb = tid >> 3, c = tid & 7, nn = n0 + c;
    float Xi = Xs[(size_t)bb*Nn + nn];
    float Mi = input[(((size_t)bb*7+1)*Tt + 0)*Nn + nn];
    sysstore(h_g + bb*Nn + nn, 0.f);
    sysstore(xin_g + bb*Nn + nn, sigm(Xi*Mi));
  }
  SIGNAL_WAIT(1);

  float zbv[8], rbv[8], hbv[8];
  #pragma unroll
  for (int c=0;c<8;c++) { zbv[c]=zb[n0+c]; rbv[c]=rb[n0+c]; hbv[c]=hb[n0+c]; }

  float zs[8], axs[8];
  float* xb = xh + b*1024;

  for (int t = 0; t < Tt; t++) {
    #pragma unroll
    for (int i = 0; i < 16; i++) {
      int bb = i >> 1;
      float v = (i & 1) ? sysload(h_g + bb*Nn + tid) : sysload(xin_g + bb*Nn + tid);
      xh[i*512 + tid] = v;
    }
    __syncthreads();
    float az[8], ar[8], ax[8];
    #pragma unroll
    for (int c=0;c<8;c++) { az[c]=0.f; ar[c]=0.f; ax[c]=0.f; }
    #pragma unroll 2
    for (int i = 0; i < 8; i++) {
      int k = i*128 + q*2;
      float2 xv = *reinterpret_cast<const float2*>(xb + k);
      #pragma unroll
      for (int c = 0; c < 8; c++) {
        float2 wz = *reinterpret_cast<const float2*>(wl + c*3072 + k);
        float2 wr = *reinterpret_cast<const float2*>(wl + c*3072 + 1024 + k);
        az[c] += xv.x*wz.x + xv.y*wz.y;
        ar[c] += xv.x*wr.x + xv.y*wr.y;
      }
    }
    #pragma unroll 2
    for (int i = 0; i < 4; i++) {
      int k = i*128 + q*2;
      float2 xv = *reinterpret_cast<const float2*>(xb + k);
      #pragma unroll
      for (int c = 0; c < 8; c++) {
        float2 wx = *reinterpret_cast<const float2*>(wl + c*3072 + 2048 + k);
        ax[c] += xv.x*wx.x + xv.y*wx.y;
      }
    }
    #pragma unroll
    for (int d = 1; d < 64; d <<= 1) {
      #pragma unroll
      for (int c = 0; c < 8; c++) {
        az[c] += __shfl_xor(az[c], d);
        ar[c] += __shfl_xor(ar[c], d);
        ax[c] += __shfl_xor(ax[c], d);
      }
    }
    if (q == 0) {
      #pragma unroll
      for (int c = 0; c < 8; c++) {
        zs[c]  = sigm(az[c] + zbv[c]);
        axs[c] = ax[c];
        float r  = sigm(ar[c] + rbv[c]);
        float hv = xb[512 + n0 + c];
        sysstore(rh_g + b*Nn + n0 + c, r*hv);
      }
    }
    SIGNAL_WAIT(2 + 2*t);
    #pragma unroll
    for (int i = 0; i < 8; i++) {
      float v = sysload(rh_g + i*Nn + tid);
      xh[i*1024 + tid] = v;
    }
    __syncthreads();
    float ah[8];
    #pragma unroll
    for (int c=0;c<8;c++) ah[c]=0.f;
    #pragma unroll 2
    for (int i = 0; i < 4; i++) {
      int k = i*128 + q*2;
      float2 rv = *reinterpret_cast<const float2*>(xb + k);
      #pragma unroll
      for (int c = 0; c < 8; c++) {
        float2 wh = *reinterpret_cast<const float2*>(wl + c*3072 + 2560 + k);
        ah[c] += rv.x*wh.x + rv.y*wh.y;
      }
    }
    #pragma unroll
    for (int d = 1; d < 64; d <<= 1) {
      #pragma unroll
      for (int c = 0; c < 8; c++) ah[c] += __shfl_xor(ah[c], d);
    }
    if (q == 0) {
      #pragma unroll
      for (int c = 0; c < 8; c++) {
        float hv = xb[512 + n0 + c];
        float ht = tanhf(axs[c] + ah[c] + hbv[c]);
        float hn = (1.f - zs[c])*hv + zs[c]*ht;
        outs[((size_t)t*Bb + b)*Nn + n0 + c] = hn;
        sysstore(h_g + b*Nn + n0 + c, hn);
        if (t+1 < Tt) {
          float Xi = Xs[((size_t)(t+1)*Bb + b)*Nn + n0 + c];
          float Mi = input[(((size_t)b*7+1)*Tt + (t+1))*Nn + n0 + c];
          sysstore(xin_g + b*Nn + n0 + c, sigm(Xi*Mi + hn*(1.f - Mi)));
        }
      }
    }
    SIGNAL_WAIT(3 + 2*t);
  }
#undef SIGNAL_WAIT
}

// ---------------- x += outs*rw + rb (after GRU) ----------------
__global__ void k_xre(float* __restrict__ x, const float* __restrict__ outs,
                      const float* __restrict__ rw, const float* __restrict__ rb2) {
  size_t idx = (size_t)blockIdx.x*256 + threadIdx.x;
  if (idx >= BTCN) return;
  int n = idx & 511;
  int c = (int)((idx >> 9) & 31);
  size_t bt = idx >> 14;
  int b = (int)(bt / Tt), t = (int)(bt % Tt);
  float o = outs[((size_t)t*Bb + b)*Nn + n];
  x[idx] += o*rw[c] + rb2[c];
}

// ---------------- head: relu(skipK) -> end1 relu -> end2 ----------------
__launch_bounds__(256)
__global__ void k_head(const float* __restrict__ skipK,
                       const float* __restrict__ e1w, const float* __restrict__ e1b,
                       const float* __restrict__ e2w, const float* __restrict__ e2b,
                       float* __restrict__ out) {
  __shared__ float sw[2048], sb[64], s2[64];
  for (int l = threadIdx.x; l < 2048; l += 256) sw[l] = e1w[l];
  if (threadIdx.x < 64) { sb[threadIdx.x] = e1b[threadIdx.x]; s2[threadIdx.x] = e2w[threadIdx.x]; }
  __syncthreads();
  int idx = blockIdx.x*256 + threadIdx.x;
  if (idx >= Bb*Kk*Tt) return;
  int t = idx % Tt;
  int k = (idx / Tt) % Kk;
  int b = idx / (Tt*Kk);
  const float* sp = skipK + (((size_t)b*Kk + k)*Cc)*Tt + t;
  float in[32];
  #pragma unroll
  for (int c=0;c<32;c++) in[c] = fmaxf(sp[(size_t)c*Tt], 0.f);
  float acc = e2b[0];
  for (int o=0;o<64;o++) {
    float s = sb[o];
    #pragma unroll
    for (int c=0;c<32;c++) s += sw[o*32+c]*in[c];
    acc += s2[o]*fmaxf(s, 0.f);
  }
  out[idx] = acc;
}

extern "C" void kernel_launch(void* const* d_in, const int* in_sizes, int n_in,
                              void* d_out, int out_size, void* d_ws, size_t ws_size,
                              hipStream_t stream) {
  const float* input = (const float*)d_in[0];
  const int*   miss  = (const int*)  d_in[1];
  const float* sup0  = (const float*)d_in[2];
  const float* sup1  = (const float*)d_in[3];
  const float* nv1   = (const float*)d_in[4];
  const float* nv2   = (const float*)d_in[5];
  const float* skw   = (const float*)d_in[6];
  const float* skb   = (const float*)d_in[7];
  const float* fw    = (const float*)d_in[8];
  const float* fb    = (const float*)d_in[9];
  const float* gw    = (const float*)d_in[10];
  const float* gb    = (const float*)d_in[11];
  const float* gcw   = (const float*)d_in[12];
  const float* gcb   = (const float*)d_in[13];
  const float* iw    = (const float*)d_in[14];
  const float* ib2   = (const float*)d_in[15];
  const float* rw    = (const float*)d_in[16];
  const float* rb2   = (const float*)d_in[17];
  const float* zl    = (const float*)d_in[18];
  const float* zb    = (const float*)d_in[19];
  const float* rl    = (const float*)d_in[20];
  const float* rb    = (const float*)d_in[21];
  const float* hl    = (const float*)d_in[22];
  const float* hb    = (const float*)d_in[23];
  const float* e1w   = (const float*)d_in[24];
  const float* e1b   = (const float*)d_in[25];
  const float* e2w   = (const float*)d_in[26];
  const float* e2b   = (const float*)d_in[27];
  float* out = (float*)d_out;

  float* p     = (float*)d_ws;
  float* x     = p; p += BTCN;
  float* xg    = p; p += BTCNc;
  float* tmp1  = p; p += BTCNc;
  float* gout  = p; p += BTCNc;
  float* skipK = p; p += (size_t)Bb*Kk*Cc*Tt;
  float* adp   = p; p += (size_t)Nn*Nn;
  float* wpack = p; p += (size_t)GRUB*8*3072;
  unsigned short* ShiT = (unsigned short*)p; p += (size_t)(3*512*512)/2;
  unsigned short* SloT = (unsigned short*)p; p += (size_t)(3*512*512)/2;
  float* Xs    = p; p += (size_t)Tt*Bb*Nn;
  float* outs  = p; p += (size_t)Tt*Bb*Nn;
  float* h_g   = p; p += Bb*Nn;
  float* xin_g = p; p += Bb*Nn;
  float* rh_g  = p; p += Bb*Nn;
  int*   flags = (int*)p; p += GRUB*32;

  k_wt2<<<(GRUB*8*3072 + 255)/256, 256, 0, stream>>>(zl, rl, hl, wpack);
  k_adp<<<Nn, 256, 0, stream>>>(nv1, nv2, adp);
  k_sprep<<<(3*512*512 + 255)/256, 256, 0, stream>>>(sup0, sup1, adp, ShiT, SloT);
  k_intransform<<<(int)((BTN + 255)/256), 256, 0, stream>>>(input, skw, skb, x);

  for (int layer = 0; layer < Ll; layer++) {
    for (int chunk = 0; chunk < NCH; chunk++) {
      k_fgconv<<<(int)((BTNc + 255)/256), 256, 0, stream>>>(
          x, fw + layer*2048, fb + layer*32, gw + layer*2048, gb + layer*32,
          gcw + layer*32*224, gcb + layer*32, xg, gout, chunk);
      for (int s = 0; s < 3; s++) {
        k_supmfma<<<dim3((BTc/2)*4), 256, 0, stream>>>(
            xg,   ShiT + s*262144, SloT + s*262144, gcw + layer*32*224, 2*s+1, tmp1, gout, 1);
        k_supmfma<<<dim3((BTc/2)*4), 256, 0, stream>>>(
            tmp1, ShiT + s*262144, SloT + s*262144, gcw + layer*32*224, 2*s+2, tmp1, gout, 0);
      }
      k_skipgather<<<(BPC*Kk*Tt + 255)/256, 256, 0, stream>>>(xg, miss, skipK, chunk, layer == 0 ? 1 : 0);
      k_ingru<<<(int)((BTNc + 255)/256), 256, 0, stream>>>(gout, iw, ib2, Xs, chunk);
      k_xfold<<<(int)((BTCNc + 255)/256), 256, 0, stream>>>(x, gout, chunk);
    }
    hipMemsetAsync(flags, 0, GRUB*32*sizeof(int), stream);
    k_gru5<<<dim3(GRUB), dim3(512), 0, stream>>>(
        Xs, input, wpack, zb, rb, hb, h_g, xin_g, rh_g, outs, flags);
    k_xre<<<(int)((BTCN + 255)/256), 256, 0, stream>>>(x, outs, rw, rb2);
  }
  k_head<<<(Bb*Kk*Tt + 255)/256, 256, 0, stream>>>(skipK, e1w, e1b, e2w, e2b, out);
}

// Round 9
// 17245.448 us; speedup vs baseline: 2.7191x; 1.2284x over previous
//
#include <hip/hip_runtime.h>
#include <math.h>

#define Bb 8
#define Tt 168
#define Nn 512
#define Cc 32
#define Ll 4
#define Kk 50
#define NCH 4
#define BPC 2                     // batches per chunk (chunk boundary = t==0, no cross-chunk reads)
#define BTc (BPC*Tt)              // 336
#define BTNc ((size_t)BTc*Nn)
#define BTCNc ((size_t)BTc*Cc*Nn)
#define BT (Bb*Tt)
#define BTN ((size_t)Bb*Tt*Nn)
#define BTCN ((size_t)Bb*Tt*Cc*Nn)
#define GRUB 64                   // GRU blocks: each owns 8 output cols, all batches

typedef __attribute__((ext_vector_type(8))) short short8v;
typedef __attribute__((ext_vector_type(4))) float f32x4;

__device__ __forceinline__ float sigm(float v) { return 1.0f/(1.0f + expf(-v)); }

__device__ __forceinline__ unsigned int f2bf(float x) {   // RNE, returns bits in low 16
  unsigned int u = __float_as_uint(x);
  u = u + 0x7FFFu + ((u >> 16) & 1u);
  return u >> 16;
}
__device__ __forceinline__ float bf2f(unsigned int h) {
  return __uint_as_float(h << 16);
}

__device__ __forceinline__ float sysload(const float* p) {
  return __hip_atomic_load(p, __ATOMIC_RELAXED, __HIP_MEMORY_SCOPE_SYSTEM);
}
__device__ __forceinline__ void sysstore(float* p, float v) {
  __hip_atomic_store(p, v, __ATOMIC_RELAXED, __HIP_MEMORY_SCOPE_SYSTEM);
}
__device__ __forceinline__ int flagload(const int* p) {
  return __hip_atomic_load(p, __ATOMIC_RELAXED, __HIP_MEMORY_SCOPE_AGENT);
}
__device__ __forceinline__ void flagstore(int* p, int v) {
  __hip_atomic_store(p, v, __ATOMIC_RELAXED, __HIP_MEMORY_SCOPE_AGENT);
}

// cache-bypassing vector ops (coherence-point data plane) — ext_vector types only,
// HIP float4 is a struct and trips "indirect register inputs" in inline asm.
__device__ __forceinline__ void byp_store4(float* p, f32x4 v) {
  asm volatile("global_store_dwordx4 %0, %1, off sc0 sc1" :: "v"(p), "v"(v) : "memory");
}

// ---------------- pack GRU weights block-sliced: wpack[sl][c][kk], kk over [z|r|hx|hh] ----------------
__global__ void k_wt2(const float* __restrict__ zl, const float* __restrict__ rl,
                      const float* __restrict__ hl, float* __restrict__ wpack) {
  int idx = blockIdx.x*256 + threadIdx.x;       // 64*8*3072 = 1572864
  if (idx >= GRUB*8*3072) return;
  int kk = idx % 3072;
  int c  = (idx / 3072) & 7;
  int sl = idx / (3072*8);
  int ncol = sl*8 + c;
  float v;
  if (kk < 1024)      v = zl[ncol*1024 + kk];
  else if (kk < 2048) v = rl[ncol*1024 + (kk-1024)];
  else if (kk < 2560) v = hl[ncol*1024 + (kk-2048)];
  else                v = hl[ncol*1024 + 512 + (kk-2560)];
  wpack[idx] = v;
}

// ---------------- adaptive adjacency: softmax(relu(nv1@nv2), axis=1) ----------------
__global__ void k_adp(const float* __restrict__ nv1, const float* __restrict__ nv2,
                      float* __restrict__ adp) {
  int i = blockIdx.x;
  __shared__ float row[512];
  __shared__ float red[256];
  float v1[10];
  #pragma unroll
  for (int k=0;k<10;k++) v1[k] = nv1[i*10+k];
  for (int jj = threadIdx.x; jj < 512; jj += 256) {
    float s = 0.f;
    #pragma unroll
    for (int k=0;k<10;k++) s += v1[k]*nv2[k*Nn + jj];
    row[jj] = fmaxf(s, 0.f);
  }
  __syncthreads();
  float m = fmaxf(row[threadIdx.x], row[threadIdx.x+256]);
  red[threadIdx.x] = m; __syncthreads();
  for (int s=128; s>0; s>>=1) { if (threadIdx.x < s) red[threadIdx.x] = fmaxf(red[threadIdx.x], red[threadIdx.x+s]); __syncthreads(); }
  float mx = red[0]; __syncthreads();
  float e0 = expf(row[threadIdx.x]      - mx);
  float e1 = expf(row[threadIdx.x+256]  - mx);
  red[threadIdx.x] = e0 + e1; __syncthreads();
  for (int s=128; s>0; s>>=1) { if (threadIdx.x < s) red[threadIdx.x] += red[threadIdx.x+s]; __syncthreads(); }
  float inv = 1.f/red[0];
  adp[(size_t)i*Nn + threadIdx.x]       = e0*inv;
  adp[(size_t)i*Nn + threadIdx.x + 256] = e1*inv;
}

// ---------------- split supports to transposed bf16 hi/lo: ShiT[s][n][k] ----------------
__global__ void k_sprep(const float* __restrict__ sup0, const float* __restrict__ sup1,
                        const float* __restrict__ adp,
                        unsigned short* __restrict__ ShiT, unsigned short* __restrict__ SloT) {
  int idx = blockIdx.x*256 + threadIdx.x;
  if (idx >= 3*512*512) return;
  int s = idx >> 18;
  int rem = idx & 262143;
  int n = rem >> 9, k = rem & 511;
  const float* S = (s==0) ? sup0 : (s==1) ? sup1 : adp;
  float v = S[k*512 + n];
  unsigned int h = f2bf(v);
  float lo = v - bf2f(h);
  ShiT[idx] = (unsigned short)h;
  SloT[idx] = (unsigned short)f2bf(lo);
}

// ---------------- input transform: x = conv1x1(input[[0,3,5,6]]) -> (B,T,C,N) ----------------
__global__ void k_intransform(const float* __restrict__ input, const float* __restrict__ skw,
                              const float* __restrict__ skb, float* __restrict__ x) {
  size_t idx = (size_t)blockIdx.x*256 + threadIdx.x;
  if (idx >= BTN) return;
  int n = idx & 511;
  size_t bt = idx >> 9;
  int b = (int)(bt / Tt), t = (int)(bt % Tt);
  size_t chs = (size_t)Tt*Nn;
  size_t base = (((size_t)b*7)*Tt + t)*Nn + n;
  float v0 = input[base + 0*chs];
  float v3 = input[base + 3*chs];
  float v5 = input[base + 5*chs];
  float v6 = input[base + 6*chs];
  float* xp = x + bt*Cc*Nn + n;
  #pragma unroll
  for (int c=0;c<32;c++)
    xp[(size_t)c*Nn] = skb[c] + skw[c*4+0]*v0 + skw[c*4+1]*v3 + skw[c*4+2]*v5 + skw[c*4+3]*v6;
}

// ---------------- fused filter/gate conv1x2 -> xg_q ; gout_q = W0@xg + bias (chunk-local) ----------------
__launch_bounds__(256)
__global__ void k_fgconv(const float* __restrict__ x, const float* __restrict__ fw,
                         const float* __restrict__ fb, const float* __restrict__ gw,
                         const float* __restrict__ gb, const float* __restrict__ gcwl,
                         const float* __restrict__ gcb,
                         float* __restrict__ xg, float* __restrict__ gout, int chunk) {
  __shared__ float sfw[2048], sgw[2048], sw0[1024], sfb[32], sgb[32], sgcb[32];
  for (int l = threadIdx.x; l < 2048; l += 256) { sfw[l] = fw[l]; sgw[l] = gw[l]; }
  for (int l = threadIdx.x; l < 1024; l += 256) sw0[l] = gcwl[(l>>5)*224 + (l&31)];
  if (threadIdx.x < 32) {
    sfb[threadIdx.x] = fb[threadIdx.x];
    sgb[threadIdx.x] = gb[threadIdx.x];
    sgcb[threadIdx.x] = gcb[threadIdx.x];
  }
  __syncthreads();
  size_t idx = (size_t)blockIdx.x*256 + threadIdx.x;
  if (idx >= BTNc) return;
  int n = idx & 511;
  size_t btl = idx >> 9;
  int t = (int)(btl % Tt);
  size_t btg = (size_t)chunk*BTc + btl;
  const float* xp = x + btg*Cc*Nn + n;
  float xl[32], xr[32];
  #pragma unroll
  for (int c=0;c<32;c++) xr[c] = xp[(size_t)c*Nn];
  if (t == 0) {
    #pragma unroll
    for (int c=0;c<32;c++) xl[c] = 0.f;
  } else {
    const float* xq = xp - (size_t)Cc*Nn;
    #pragma unroll
    for (int c=0;c<32;c++) xl[c] = xq[(size_t)c*Nn];
  }
  float xgv[32];
  for (int c=0;c<32;c++) {
    float f = sfb[c], g = sgb[c];
    #pragma unroll
    for (int cp=0;cp<32;cp++) {
      f += xl[cp]*sfw[(c*32+cp)*2] + xr[cp]*sfw[(c*32+cp)*2+1];
      g += xl[cp]*sgw[(c*32+cp)*2] + xr[cp]*sgw[(c*32+cp)*2+1];
    }
    xgv[c] = tanhf(f) * sigm(g);
  }
  float* xgp = xg + btl*Cc*Nn + n;
  #pragma unroll
  for (int c=0;c<32;c++) xgp[(size_t)c*Nn] = xgv[c];
  float* gp = gout + btl*Cc*Nn + n;
  for (int o=0;o<32;o++) {
    float s = sgcb[o];
    #pragma unroll
    for (int c=0;c<32;c++) s += sw0[o*32+c]*xgv[c];
    gp[(size_t)o*Nn] = s;
  }
}

// ---------------- support GEMM via split-bf16 MFMA ----------------
__launch_bounds__(256)
__global__ void k_supmfma(const float* __restrict__ X,
                          const unsigned short* __restrict__ ShiT,
                          const unsigned short* __restrict__ SloT,
                          const float* __restrict__ gcw, int pslot,
                          float* __restrict__ Y, float* __restrict__ gout, int storeY) {
  __shared__ unsigned char smem[64*132*4];      // pool: staging (30720B) then sY (33792B)
  __shared__ float sW[1024];
  unsigned short* sXhi = (unsigned short*)smem;                 // 64*40
  unsigned short* sXlo = sXhi + 2560;
  unsigned short* sShi = sXlo + 2560;                           // 128*40
  unsigned short* sSlo = sShi + 5120;
  float* sY = (float*)smem;                                     // 64*132 (after K loop)
#define MW 40

  const int tid  = threadIdx.x;
  const int bt2  = blockIdx.x >> 2;
  const int colg = blockIdx.x & 3;
  const int bt0  = bt2*2;
  const int n0   = colg*128;
  const int lane = tid & 63, wv = tid >> 6;
  const int kb   = (lane >> 4)*8;

  for (int l = tid; l < 1024; l += 256)
    sW[l] = gcw[(l>>5)*224 + pslot*32 + (l&31)];

  f32x4 acc[4][2];
  #pragma unroll
  for (int i=0;i<4;i++) {
    #pragma unroll
    for (int j=0;j<2;j++) { acc[i][j].x=0.f; acc[i][j].y=0.f; acc[i][j].z=0.f; acc[i][j].w=0.f; }
  }

  const int sm  = tid >> 2;              // X stage: row 0..63
  const int skp = (tid & 3)*8;           // k part
  const size_t xrow = ((size_t)(bt0 + (sm>>5))*Cc + (sm&31))*Nn;
  const int sn  = tid >> 1;              // S stage: col-row 0..127
  const int shp = (tid & 1)*16;          // 16-k half

  for (int kc = 0; kc < 16; kc++) {
    const int k0 = kc*32;
    {
      float4 a0 = *reinterpret_cast<const float4*>(&X[xrow + k0 + skp]);
      float4 a1 = *reinterpret_cast<const float4*>(&X[xrow + k0 + skp + 4]);
      float v[8] = {a0.x,a0.y,a0.z,a0.w,a1.x,a1.y,a1.z,a1.w};
      unsigned int h[8], l[8];
      #pragma unroll
      for (int i=0;i<8;i++) {
        h[i] = f2bf(v[i]);
        l[i] = f2bf(v[i] - bf2f(h[i]));
      }
      uint4 H = { h[0]|(h[1]<<16), h[2]|(h[3]<<16), h[4]|(h[5]<<16), h[6]|(h[7]<<16) };
      uint4 L = { l[0]|(l[1]<<16), l[2]|(l[3]<<16), l[4]|(l[5]<<16), l[6]|(l[7]<<16) };
      *reinterpret_cast<uint4*>(&sXhi[sm*MW + skp]) = H;
      *reinterpret_cast<uint4*>(&sXlo[sm*MW + skp]) = L;
    }
    {
      const size_t srow = (size_t)(n0 + sn)*512 + k0 + shp;
      *reinterpret_cast<uint4*>(&sShi[sn*MW + shp])     = *reinterpret_cast<const uint4*>(&ShiT[srow]);
      *reinterpret_cast<uint4*>(&sShi[sn*MW + shp + 8]) = *reinterpret_cast<const uint4*>(&ShiT[srow + 8]);
      *reinterpret_cast<uint4*>(&sSlo[sn*MW + shp])     = *reinterpret_cast<const uint4*>(&SloT[srow]);
      *reinterpret_cast<uint4*>(&sSlo[sn*MW + shp + 8]) = *reinterpret_cast<const uint4*>(&SloT[srow + 8]);
    }
    __syncthreads();
    short8v bhi[2], blo[2];
    #pragma unroll
    for (int ct=0; ct<2; ct++) {
      int col = wv*32 + ct*16 + (lane & 15);
      bhi[ct] = *reinterpret_cast<const short8v*>(&sShi[col*MW + kb]);
      blo[ct] = *reinterpret_cast<const short8v*>(&sSlo[col*MW + kb]);
    }
    #pragma unroll
    for (int rt=0; rt<4; rt++) {
      int row = rt*16 + (lane & 15);
      short8v ahi = *reinterpret_cast<const short8v*>(&sXhi[row*MW + kb]);
      short8v alo = *reinterpret_cast<const short8v*>(&sXlo[row*MW + kb]);
      #pragma unroll
      for (int ct=0; ct<2; ct++) {
        acc[rt][ct] = __builtin_amdgcn_mfma_f32_16x16x32_bf16(ahi, bhi[ct], acc[rt][ct], 0, 0, 0);
        acc[rt][ct] = __builtin_amdgcn_mfma_f32_16x16x32_bf16(ahi, blo[ct], acc[rt][ct], 0, 0, 0);
        acc[rt][ct] = __builtin_amdgcn_mfma_f32_16x16x32_bf16(alo, bhi[ct], acc[rt][ct], 0, 0, 0);
      }
    }
    __syncthreads();
  }
  #pragma unroll
  for (int rt=0; rt<4; rt++) {
    #pragma unroll
    for (int ct=0; ct<2; ct++) {
      int col = wv*32 + ct*16 + (lane & 15);
      int rbase = rt*16 + (lane >> 4)*4;
      sY[(rbase+0)*132 + col] = acc[rt][ct].x;
      sY[(rbase+1)*132 + col] = acc[rt][ct].y;
      sY[(rbase+2)*132 + col] = acc[rt][ct].z;
      sY[(rbase+3)*132 + col] = acc[rt][ct].w;
    }
  }
  __syncthreads();
  if (storeY) {
    for (int e = tid; e < 2048; e += 256) {
      int m = e >> 5, c4 = (e & 31)*4;
      float4 v = *reinterpret_cast<const float4*>(&sY[m*132 + c4]);
      *reinterpret_cast<float4*>(&Y[((size_t)(bt0 + (m>>5))*Cc + (m&31))*Nn + n0 + c4]) = v;
    }
  }
  {
    int tx = tid & 31, ty = tid >> 5;
    for (int btl = 0; btl < 2; btl++) {
      float og[4][4];
      #pragma unroll
      for (int i=0;i<4;i++) { og[i][0]=0.f; og[i][1]=0.f; og[i][2]=0.f; og[i][3]=0.f; }
      #pragma unroll 8
      for (int c = 0; c < 32; c++) {
        float4 yv = *reinterpret_cast<const float4*>(&sY[(btl*32 + c)*132 + tx*4]);
        float w0 = sW[((ty<<2)+0)*32 + c];
        float w1 = sW[((ty<<2)+1)*32 + c];
        float w2 = sW[((ty<<2)+2)*32 + c];
        float w3 = sW[((ty<<2)+3)*32 + c];
        og[0][0]+=w0*yv.x; og[0][1]+=w0*yv.y; og[0][2]+=w0*yv.z; og[0][3]+=w0*yv.w;
        og[1][0]+=w1*yv.x; og[1][1]+=w1*yv.y; og[1][2]+=w1*yv.z; og[1][3]+=w1*yv.w;
        og[2][0]+=w2*yv.x; og[2][1]+=w2*yv.y; og[2][2]+=w2*yv.z; og[2][3]+=w2*yv.w;
        og[3][0]+=w3*yv.x; og[3][1]+=w3*yv.y; og[3][2]+=w3*yv.z; og[3][3]+=w3*yv.w;
      }
      float* gp = gout + (size_t)(bt0+btl)*Cc*Nn + n0 + (tx<<2);
      #pragma unroll
      for (int i=0;i<4;i++) {
        float4 cur = *reinterpret_cast<float4*>(gp + (size_t)((ty<<2)+i)*Nn);
        cur.x += og[i][0]; cur.y += og[i][1]; cur.z += og[i][2]; cur.w += og[i][3];
        *reinterpret_cast<float4*>(gp + (size_t)((ty<<2)+i)*Nn) = cur;
      }
    }
  }
#undef MW
}

// ---------------- skip gather: skipK[b,k,c,t] (+)= xg_q[btl,c,node] ----------------
__global__ void k_skipgather(const float* __restrict__ xg, const int* __restrict__ miss,
                             float* __restrict__ skipK, int chunk, int first) {
  int idx = blockIdx.x*256 + threadIdx.x;
  if (idx >= BPC*Kk*Tt) return;
  int t = idx % Tt;
  int k = (idx / Tt) % Kk;
  int bloc = idx / (Tt*Kk);
  int bg = chunk*BPC + bloc;
  int node = miss[bg*Kk + k];
  const float* xp = xg + (((size_t)bloc*Tt + t)*Cc)*Nn + node;
  float* sp = skipK + (((size_t)bg*Kk + k)*Cc)*Tt + t;
  #pragma unroll
  for (int c=0;c<32;c++) {
    float v = xp[(size_t)c*Nn];
    sp[(size_t)c*Tt] = first ? v : (sp[(size_t)c*Tt] + v);
  }
}

// ---------------- ingru: Xs[t,b,n] = sum_c gout_q*iw + ib ----------------
__global__ void k_ingru(const float* __restrict__ gout, const float* __restrict__ iw,
                        const float* __restrict__ ib2, float* __restrict__ Xs, int chunk) {
  size_t idx = (size_t)blockIdx.x*256 + threadIdx.x;
  if (idx >= BTNc) return;
  int n = idx & 511;
  size_t btl = idx >> 9;
  int b = chunk*BPC + (int)(btl / Tt), t = (int)(btl % Tt);
  const float* gp = gout + btl*Cc*Nn + n;
  float s = ib2[0];
  #pragma unroll
  for (int c=0;c<Cc;c++) s += iw[c]*gp[(size_t)c*Nn];
  Xs[((size_t)t*Bb + b)*Nn + n] = s;
}

// ---------------- x += gout_q (chunk fold) ----------------
__global__ void k_xfold(float* __restrict__ x, const float* __restrict__ gout, int chunk) {
  size_t idx = (size_t)blockIdx.x*256 + threadIdx.x;
  if (idx >= BTCNc) return;
  x[(size_t)chunk*BTCNc + idx] += gout[idx];
}

// ---------------- GRU v6: weights in LDS + VECTORIZED bypass exchange + AGENT flags ----------------
__launch_bounds__(512, 1)
__global__ void k_gru6(const float* __restrict__ Xs, const float* __restrict__ input,
                       const float* __restrict__ wpack,
                       const float* __restrict__ zb, const float* __restrict__ rb,
                       const float* __restrict__ hb,
                       float* __restrict__ xh_g,      // [b][ xin 0:512 | h 512:1024 ]
                       float* __restrict__ rh_g,      // [b][512]
                       float* __restrict__ outs,
                       int* __restrict__ flags) {
  __shared__ float wl[8*3072];   // 96KB weights
  __shared__ float xh[8*1024];   // 32KB xin|h
  __shared__ float rhl[8*512];   // 16KB rh
  const int tid = threadIdx.x;
  const int sl  = blockIdx.x;
  const int n0  = sl*8;
  const int b   = tid >> 6;
  const int q   = tid & 63;
  int* myflag = flags + sl*32;

#define SIGNAL_WAIT(v) do { \
    asm volatile("s_waitcnt vmcnt(0)" ::: "memory"); \
    __syncthreads(); \
    if (tid == 0) flagstore(myflag, (v)); \
    if (tid < GRUB) { \
      const int* fl = flags + tid*32; \
      while (flagload(fl) < (v)) __builtin_amdgcn_s_sleep(1); \
    } \
    __syncthreads(); \
  } while (0)

  // stage weights once
  {
    const float4* src = reinterpret_cast<const float4*>(wpack + (size_t)sl*24576);
    float4* dst = reinterpret_cast<float4*>(wl);
    #pragma unroll 4
    for (int i = tid; i < 6144; i += 512) dst[i] = src[i];
  }
  // t=0 init for own cols
  if (tid < 64) {
    int bb = tid >> 3, c = tid & 7, nn = n0 + c;
    float Xi = Xs[(size_t)bb*Nn + nn];
    float Mi = input[(((size_t)bb*7+1)*Tt + 0)*Nn + nn];
    sysstore(xh_g + bb*1024 + 512 + nn, 0.f);
    sysstore(xh_g + bb*1024 + nn, sigm(Xi*Mi));
  }
  SIGNAL_WAIT(1);

  float zbv[8], rbv[8], hbv[8];
  #pragma unroll
  for (int c=0;c<8;c++) { zbv[c]=zb[n0+c]; rbv[c]=rb[n0+c]; hbv[c]=hb[n0+c]; }

  float zs[8], axs[8];
  float* xb = xh + b*1024;
  float* rb_l = rhl + b*512;

  for (int t = 0; t < Tt; t++) {
    // prefetch next-step Xs/M for own cols (regular cached loads, off critical path)
    float4 xiA, xiB, miA, miB;
    {
      int tp = (t+1 < Tt) ? (t+1) : t;
      const float* xsp = Xs + ((size_t)tp*Bb + b)*Nn + n0;
      const float* mip = input + (((size_t)b*7+1)*Tt + tp)*Nn + n0;
      xiA = *reinterpret_cast<const float4*>(xsp);
      xiB = *reinterpret_cast<const float4*>(xsp + 4);
      miA = *reinterpret_cast<const float4*>(mip);
      miB = *reinterpret_cast<const float4*>(mip + 4);
    }
    // ---- stage xh_g -> LDS: 4 parallel bypass dwordx4 per thread, one drain ----
    {
      const float* p0 = xh_g + (size_t)(0*512 + tid)*4;
      const float* p1 = xh_g + (size_t)(1*512 + tid)*4;
      const float* p2 = xh_g + (size_t)(2*512 + tid)*4;
      const float* p3 = xh_g + (size_t)(3*512 + tid)*4;
      f32x4 v0, v1, v2, v3;
      asm volatile(
        "global_load_dwordx4 %0, %4, off sc0 sc1\n\t"
        "global_load_dwordx4 %1, %5, off sc0 sc1\n\t"
        "global_load_dwordx4 %2, %6, off sc0 sc1\n\t"
        "global_load_dwordx4 %3, %7, off sc0 sc1\n\t"
        "s_waitcnt vmcnt(0)"
        : "=&v"(v0), "=&v"(v1), "=&v"(v2), "=&v"(v3)
        : "v"(p0), "v"(p1), "v"(p2), "v"(p3)
        : "memory");
      *reinterpret_cast<f32x4*>(&xh[(0*512 + tid)*4]) = v0;
      *reinterpret_cast<f32x4*>(&xh[(1*512 + tid)*4]) = v1;
      *reinterpret_cast<f32x4*>(&xh[(2*512 + tid)*4]) = v2;
      *reinterpret_cast<f32x4*>(&xh[(3*512 + tid)*4]) = v3;
    }
    __syncthreads();
    // ---- phase A: z, r (K=1024), hx (K=512) ----
    float az[8], ar[8], ax[8];
    #pragma unroll
    for (int c=0;c<8;c++) { az[c]=0.f; ar[c]=0.f; ax[c]=0.f; }
    #pragma unroll 2
    for (int i = 0; i < 8; i++) {
      int k = i*128 + q*2;
      float2 xv = *reinterpret_cast<const float2*>(xb + k);
      #pragma unroll
      for (int c = 0; c < 8; c++) {
        float2 wz = *reinterpret_cast<const float2*>(wl + c*3072 + k);
        float2 wr = *reinterpret_cast<const float2*>(wl + c*3072 + 1024 + k);
        az[c] += xv.x*wz.x + xv.y*wz.y;
        ar[c] += xv.x*wr.x + xv.y*wr.y;
      }
    }
    #pragma unroll 2
    for (int i = 0; i < 4; i++) {
      int k = i*128 + q*2;
      float2 xv = *reinterpret_cast<const float2*>(xb + k);
      #pragma unroll
      for (int c = 0; c < 8; c++) {
        float2 wx = *reinterpret_cast<const float2*>(wl + c*3072 + 2048 + k);
        ax[c] += xv.x*wx.x + xv.y*wx.y;
      }
    }
    #pragma unroll
    for (int d = 1; d < 64; d <<= 1) {
      #pragma unroll
      for (int c = 0; c < 8; c++) {
        az[c] += __shfl_xor(az[c], d);
        ar[c] += __shfl_xor(ar[c], d);
        ax[c] += __shfl_xor(ax[c], d);
      }
    }
    if (q == 0) {
      float rh[8];
      #pragma unroll
      for (int c = 0; c < 8; c++) {
        zs[c]  = sigm(az[c] + zbv[c]);
        axs[c] = ax[c];
        float r  = sigm(ar[c] + rbv[c]);
        rh[c] = r * xb[512 + n0 + c];
      }
      f32x4 r0 = {rh[0],rh[1],rh[2],rh[3]};
      f32x4 r1 = {rh[4],rh[5],rh[6],rh[7]};
      byp_store4(rh_g + b*512 + n0,     r0);
      byp_store4(rh_g + b*512 + n0 + 4, r1);
    }
    SIGNAL_WAIT(2 + 2*t);
    // ---- stage rh_g -> LDS: 2 parallel bypass dwordx4 ----
    {
      const float* p0 = rh_g + (size_t)(0*512 + tid)*4;
      const float* p1 = rh_g + (size_t)(1*512 + tid)*4;
      f32x4 v0, v1;
      asm volatile(
        "global_load_dwordx4 %0, %2, off sc0 sc1\n\t"
        "global_load_dwordx4 %1, %3, off sc0 sc1\n\t"
        "s_waitcnt vmcnt(0)"
        : "=&v"(v0), "=&v"(v1)
        : "v"(p0), "v"(p1)
        : "memory");
      *reinterpret_cast<f32x4*>(&rhl[(0*512 + tid)*4]) = v0;
      *reinterpret_cast<f32x4*>(&rhl[(1*512 + tid)*4]) = v1;
    }
    __syncthreads();
    // ---- phase B: hh (K=512) + combine ----
    float ah[8];
    #pragma unroll
    for (int c=0;c<8;c++) ah[c]=0.f;
    #pragma unroll 2
    for (int i = 0; i < 4; i++) {
      int k = i*128 + q*2;
      float2 rv = *reinterpret_cast<const float2*>(rb_l + k);
      #pragma unroll
      for (int c = 0; c < 8; c++) {
        float2 wh = *reinterpret_cast<const float2*>(wl + c*3072 + 2560 + k);
        ah[c] += rv.x*wh.x + rv.y*wh.y;
      }
    }
    #pragma unroll
    for (int d = 1; d < 64; d <<= 1) {
      #pragma unroll
      for (int c = 0; c < 8; c++) ah[c] += __shfl_xor(ah[c], d);
    }
    if (q == 0) {
      float hn[8];
      #pragma unroll
      for (int c = 0; c < 8; c++) {
        float hv = xb[512 + n0 + c];
        float ht = tanhf(axs[c] + ah[c] + hbv[c]);
        hn[c] = (1.f - zs[c])*hv + zs[c]*ht;
      }
      f32x4 h0 = {hn[0],hn[1],hn[2],hn[3]};
      f32x4 h1 = {hn[4],hn[5],hn[6],hn[7]};
      *reinterpret_cast<f32x4*>(&outs[((size_t)t*Bb + b)*Nn + n0])     = h0;
      *reinterpret_cast<f32x4*>(&outs[((size_t)t*Bb + b)*Nn + n0 + 4]) = h1;
      byp_store4(xh_g + b*1024 + 512 + n0,     h0);
      byp_store4(xh_g + b*1024 + 512 + n0 + 4, h1);
      if (t+1 < Tt) {
        f32x4 x0, x1;
        x0.x = sigm(xiA.x*miA.x + hn[0]*(1.f - miA.x));
        x0.y = sigm(xiA.y*miA.y + hn[1]*(1.f - miA.y));
        x0.z = sigm(xiA.z*miA.z + hn[2]*(1.f - miA.z));
        x0.w = sigm(xiA.w*miA.w + hn[3]*(1.f - miA.w));
        x1.x = sigm(xiB.x*miB.x + hn[4]*(1.f - miB.x));
        x1.y = sigm(xiB.y*miB.y + hn[5]*(1.f - miB.y));
        x1.z = sigm(xiB.z*miB.z + hn[6]*(1.f - miB.z));
        x1.w = sigm(xiB.w*miB.w + hn[7]*(1.f - miB.w));
        byp_store4(xh_g + b*1024 + n0,     x0);
        byp_store4(xh_g + b*1024 + n0 + 4, x1);
      }
    }
    SIGNAL_WAIT(3 + 2*t);
  }
#undef SIGNAL_WAIT
}

// ---------------- x += outs*rw + rb (after GRU) ----------------
__global__ void k_xre(float* __restrict__ x, const float* __restrict__ outs,
                      const float* __restrict__ rw, const float* __restrict__ rb2) {
  size_t idx = (size_t)blockIdx.x*256 + threadIdx.x;
  if (idx >= BTCN) return;
  int n = idx & 511;
  int c = (int)((idx >> 9) & 31);
  size_t bt = idx >> 14;
  int b = (int)(bt / Tt), t = (int)(bt % Tt);
  float o = outs[((size_t)t*Bb + b)*Nn + n];
  x[idx] += o*rw[c] + rb2[c];
}

// ---------------- head: relu(skipK) -> end1 relu -> end2 ----------------
__launch_bounds__(256)
__global__ void k_head(const float* __restrict__ skipK,
                       const float* __restrict__ e1w, const float* __restrict__ e1b,
                       const float* __restrict__ e2w, const float* __restrict__ e2b,
                       float* __restrict__ out) {
  __shared__ float sw[2048], sb[64], s2[64];
  for (int l = threadIdx.x; l < 2048; l += 256) sw[l] = e1w[l];
  if (threadIdx.x < 64) { sb[threadIdx.x] = e1b[threadIdx.x]; s2[threadIdx.x] = e2w[threadIdx.x]; }
  __syncthreads();
  int idx = blockIdx.x*256 + threadIdx.x;
  if (idx >= Bb*Kk*Tt) return;
  int t = idx % Tt;
  int k = (idx / Tt) % Kk;
  int b = idx / (Tt*Kk);
  const float* sp = skipK + (((size_t)b*Kk + k)*Cc)*Tt + t;
  float in[32];
  #pragma unroll
  for (int c=0;c<32;c++) in[c] = fmaxf(sp[(size_t)c*Tt], 0.f);
  float acc = e2b[0];
  for (int o=0;o<64;o++) {
    float s = sb[o];
    #pragma unroll
    for (int c=0;c<32;c++) s += sw[o*32+c]*in[c];
    acc += s2[o]*fmaxf(s, 0.f);
  }
  out[idx] = acc;
}

extern "C" void kernel_launch(void* const* d_in, const int* in_sizes, int n_in,
                              void* d_out, int out_size, void* d_ws, size_t ws_size,
                              hipStream_t stream) {
  const float* input = (const float*)d_in[0];
  const int*   miss  = (const int*)  d_in[1];
  const float* sup0  = (const float*)d_in[2];
  const float* sup1  = (const float*)d_in[3];
  const float* nv1   = (const float*)d_in[4];
  const float* nv2   = (const float*)d_in[5];
  const float* skw   = (const float*)d_in[6];
  const float* skb   = (const float*)d_in[7];
  const float* fw    = (const float*)d_in[8];
  const float* fb    = (const float*)d_in[9];
  const float* gw    = (const float*)d_in[10];
  const float* gb    = (const float*)d_in[11];
  const float* gcw   = (const float*)d_in[12];
  const float* gcb   = (const float*)d_in[13];
  const float* iw    = (const float*)d_in[14];
  const float* ib2   = (const float*)d_in[15];
  const float* rw    = (const float*)d_in[16];
  const float* rb2   = (const float*)d_in[17];
  const float* zl    = (const float*)d_in[18];
  const float* zb    = (const float*)d_in[19];
  const float* rl    = (const float*)d_in[20];
  const float* rb    = (const float*)d_in[21];
  const float* hl    = (const float*)d_in[22];
  const float* hb    = (const float*)d_in[23];
  const float* e1w   = (const float*)d_in[24];
  const float* e1b   = (const float*)d_in[25];
  const float* e2w   = (const float*)d_in[26];
  const float* e2b   = (const float*)d_in[27];
  float* out = (float*)d_out;

  float* p     = (float*)d_ws;
  float* x     = p; p += BTCN;
  float* xg    = p; p += BTCNc;
  float* tmp1  = p; p += BTCNc;
  float* gout  = p; p += BTCNc;
  float* skipK = p; p += (size_t)Bb*Kk*Cc*Tt;
  float* adp   = p; p += (size_t)Nn*Nn;
  float* wpack = p; p += (size_t)GRUB*8*3072;
  unsigned short* ShiT = (unsigned short*)p; p += (size_t)(3*512*512)/2;
  unsigned short* SloT = (unsigned short*)p; p += (size_t)(3*512*512)/2;
  float* Xs    = p; p += (size_t)Tt*Bb*Nn;
  float* outs  = p; p += (size_t)Tt*Bb*Nn;
  float* xh_g  = p; p += Bb*1024;
  float* rh_g  = p; p += Bb*512;
  int*   flags = (int*)p; p += GRUB*32;

  k_wt2<<<(GRUB*8*3072 + 255)/256, 256, 0, stream>>>(zl, rl, hl, wpack);
  k_adp<<<Nn, 256, 0, stream>>>(nv1, nv2, adp);
  k_sprep<<<(3*512*512 + 255)/256, 256, 0, stream>>>(sup0, sup1, adp, ShiT, SloT);
  k_intransform<<<(int)((BTN + 255)/256), 256, 0, stream>>>(input, skw, skb, x);

  for (int layer = 0; layer < Ll; layer++) {
    for (int chunk = 0; chunk < NCH; chunk++) {
      k_fgconv<<<(int)((BTNc + 255)/256), 256, 0, stream>>>(
          x, fw + layer*2048, fb + layer*32, gw + layer*2048, gb + layer*32,
          gcw + layer*32*224, gcb + layer*32, xg, gout, chunk);
      for (int s = 0; s < 3; s++) {
        k_supmfma<<<dim3((BTc/2)*4), 256, 0, stream>>>(
            xg,   ShiT + s*262144, SloT + s*262144, gcw + layer*32*224, 2*s+1, tmp1, gout, 1);
        k_supmfma<<<dim3((BTc/2)*4), 256, 0, stream>>>(
            tmp1, ShiT + s*262144, SloT + s*262144, gcw + layer*32*224, 2*s+2, tmp1, gout, 0);
      }
      k_skipgather<<<(BPC*Kk*Tt + 255)/256, 256, 0, stream>>>(xg, miss, skipK, chunk, layer == 0 ? 1 : 0);
      k_ingru<<<(int)((BTNc + 255)/256), 256, 0, stream>>>(gout, iw, ib2, Xs, chunk);
      k_xfold<<<(int)((BTCNc + 255)/256), 256, 0, stream>>>(x, gout, chunk);
    }
    (void)hipMemsetAsync(flags, 0, GRUB*32*sizeof(int), stream);
    k_gru6<<<dim3(GRUB), dim3(512), 0, stream>>>(
        Xs, input, wpack, zb, rb, hb, xh_g, rh_g, outs, flags);
    k_xre<<<(int)((BTCN + 255)/256), 256, 0, stream>>>(x, outs, rw, rb2);
  }
  k_head<<<(Bb*Kk*Tt + 255)/256, 256, 0, stream>>>(skipK, e1w, e1b, e2w, e2b, out);
}

// Round 10
// 14939.836 us; speedup vs baseline: 3.1388x; 1.1543x over previous
//
#include <hip/hip_runtime.h>
#include <math.h>

#define Bb 8
#define Tt 168
#define Nn 512
#define Cc 32
#define Ll 4
#define Kk 50
#define NCH 4
#define BPC 2                     // batches per chunk (chunk boundary = t==0, no cross-chunk reads)
#define BTc (BPC*Tt)              // 336
#define BTNc ((size_t)BTc*Nn)
#define BTCNc ((size_t)BTc*Cc*Nn)
#define BT (Bb*Tt)
#define BTN ((size_t)Bb*Tt*Nn)
#define BTCN ((size_t)Bb*Tt*Cc*Nn)
#define GRUB 64                   // GRU blocks: each owns 8 output cols, all batches

typedef __attribute__((ext_vector_type(8))) short short8v;
typedef __attribute__((ext_vector_type(4))) float f32x4;
typedef __attribute__((ext_vector_type(2))) float f32x2;

__device__ __forceinline__ float sigm(float v) { return 1.0f/(1.0f + expf(-v)); }

__device__ __forceinline__ unsigned int f2bf(float x) {   // RNE, returns bits in low 16
  unsigned int u = __float_as_uint(x);
  u = u + 0x7FFFu + ((u >> 16) & 1u);
  return u >> 16;
}
__device__ __forceinline__ float bf2f(unsigned int h) {
  return __uint_as_float(h << 16);
}

__device__ __forceinline__ float sysload(const float* p) {
  return __hip_atomic_load(p, __ATOMIC_RELAXED, __HIP_MEMORY_SCOPE_SYSTEM);
}
__device__ __forceinline__ void sysstore(float* p, float v) {
  __hip_atomic_store(p, v, __ATOMIC_RELAXED, __HIP_MEMORY_SCOPE_SYSTEM);
}
__device__ __forceinline__ int flagload(const int* p) {
  return __hip_atomic_load(p, __ATOMIC_RELAXED, __HIP_MEMORY_SCOPE_AGENT);
}
__device__ __forceinline__ void flagstore(int* p, int v) {
  __hip_atomic_store(p, v, __ATOMIC_RELAXED, __HIP_MEMORY_SCOPE_AGENT);
}

// cache-bypassing vector store (coherence-point data plane)
__device__ __forceinline__ void byp_store4(float* p, f32x4 v) {
  asm volatile("global_store_dwordx4 %0, %1, off sc0 sc1" :: "v"(p), "v"(v) : "memory");
}

// ---------------- pack GRU weights block-sliced: wpack[sl][c][kk], kk over [z|r|hx|hh] ----------------
__global__ void k_wt2(const float* __restrict__ zl, const float* __restrict__ rl,
                      const float* __restrict__ hl, float* __restrict__ wpack) {
  int idx = blockIdx.x*256 + threadIdx.x;       // 64*8*3072 = 1572864
  if (idx >= GRUB*8*3072) return;
  int kk = idx % 3072;
  int c  = (idx / 3072) & 7;
  int sl = idx / (3072*8);
  int ncol = sl*8 + c;
  float v;
  if (kk < 1024)      v = zl[ncol*1024 + kk];
  else if (kk < 2048) v = rl[ncol*1024 + (kk-1024)];
  else if (kk < 2560) v = hl[ncol*1024 + (kk-2048)];
  else                v = hl[ncol*1024 + 512 + (kk-2560)];
  wpack[idx] = v;
}

// ---------------- adaptive adjacency: softmax(relu(nv1@nv2), axis=1) ----------------
__global__ void k_adp(const float* __restrict__ nv1, const float* __restrict__ nv2,
                      float* __restrict__ adp) {
  int i = blockIdx.x;
  __shared__ float row[512];
  __shared__ float red[256];
  float v1[10];
  #pragma unroll
  for (int k=0;k<10;k++) v1[k] = nv1[i*10+k];
  for (int jj = threadIdx.x; jj < 512; jj += 256) {
    float s = 0.f;
    #pragma unroll
    for (int k=0;k<10;k++) s += v1[k]*nv2[k*Nn + jj];
    row[jj] = fmaxf(s, 0.f);
  }
  __syncthreads();
  float m = fmaxf(row[threadIdx.x], row[threadIdx.x+256]);
  red[threadIdx.x] = m; __syncthreads();
  for (int s=128; s>0; s>>=1) { if (threadIdx.x < s) red[threadIdx.x] = fmaxf(red[threadIdx.x], red[threadIdx.x+s]); __syncthreads(); }
  float mx = red[0]; __syncthreads();
  float e0 = expf(row[threadIdx.x]      - mx);
  float e1 = expf(row[threadIdx.x+256]  - mx);
  red[threadIdx.x] = e0 + e1; __syncthreads();
  for (int s=128; s>0; s>>=1) { if (threadIdx.x < s) red[threadIdx.x] += red[threadIdx.x+s]; __syncthreads(); }
  float inv = 1.f/red[0];
  adp[(size_t)i*Nn + threadIdx.x]       = e0*inv;
  adp[(size_t)i*Nn + threadIdx.x + 256] = e1*inv;
}

// ---------------- split supports to transposed bf16 hi/lo: ShiT[s][n][k] ----------------
__global__ void k_sprep(const float* __restrict__ sup0, const float* __restrict__ sup1,
                        const float* __restrict__ adp,
                        unsigned short* __restrict__ ShiT, unsigned short* __restrict__ SloT) {
  int idx = blockIdx.x*256 + threadIdx.x;
  if (idx >= 3*512*512) return;
  int s = idx >> 18;
  int rem = idx & 262143;
  int n = rem >> 9, k = rem & 511;
  const float* S = (s==0) ? sup0 : (s==1) ? sup1 : adp;
  float v = S[k*512 + n];
  unsigned int h = f2bf(v);
  float lo = v - bf2f(h);
  ShiT[idx] = (unsigned short)h;
  SloT[idx] = (unsigned short)f2bf(lo);
}

// ---------------- input transform: x = conv1x1(input[[0,3,5,6]]) -> (B,T,C,N) ----------------
__global__ void k_intransform(const float* __restrict__ input, const float* __restrict__ skw,
                              const float* __restrict__ skb, float* __restrict__ x) {
  size_t idx = (size_t)blockIdx.x*256 + threadIdx.x;
  if (idx >= BTN) return;
  int n = idx & 511;
  size_t bt = idx >> 9;
  int b = (int)(bt / Tt), t = (int)(bt % Tt);
  size_t chs = (size_t)Tt*Nn;
  size_t base = (((size_t)b*7)*Tt + t)*Nn + n;
  float v0 = input[base + 0*chs];
  float v3 = input[base + 3*chs];
  float v5 = input[base + 5*chs];
  float v6 = input[base + 6*chs];
  float* xp = x + bt*Cc*Nn + n;
  #pragma unroll
  for (int c=0;c<32;c++)
    xp[(size_t)c*Nn] = skb[c] + skw[c*4+0]*v0 + skw[c*4+1]*v3 + skw[c*4+2]*v5 + skw[c*4+3]*v6;
}

// ---------------- fused filter/gate conv1x2 -> xg_q ; gout_q = W0@xg + bias (chunk-local) ----------------
__launch_bounds__(256)
__global__ void k_fgconv(const float* __restrict__ x, const float* __restrict__ fw,
                         const float* __restrict__ fb, const float* __restrict__ gw,
                         const float* __restrict__ gb, const float* __restrict__ gcwl,
                         const float* __restrict__ gcb,
                         float* __restrict__ xg, float* __restrict__ gout, int chunk) {
  __shared__ float sfw[2048], sgw[2048], sw0[1024], sfb[32], sgb[32], sgcb[32];
  for (int l = threadIdx.x; l < 2048; l += 256) { sfw[l] = fw[l]; sgw[l] = gw[l]; }
  for (int l = threadIdx.x; l < 1024; l += 256) sw0[l] = gcwl[(l>>5)*224 + (l&31)];
  if (threadIdx.x < 32) {
    sfb[threadIdx.x] = fb[threadIdx.x];
    sgb[threadIdx.x] = gb[threadIdx.x];
    sgcb[threadIdx.x] = gcb[threadIdx.x];
  }
  __syncthreads();
  size_t idx = (size_t)blockIdx.x*256 + threadIdx.x;
  if (idx >= BTNc) return;
  int n = idx & 511;
  size_t btl = idx >> 9;
  int t = (int)(btl % Tt);
  size_t btg = (size_t)chunk*BTc + btl;
  const float* xp = x + btg*Cc*Nn + n;
  float xl[32], xr[32];
  #pragma unroll
  for (int c=0;c<32;c++) xr[c] = xp[(size_t)c*Nn];
  if (t == 0) {
    #pragma unroll
    for (int c=0;c<32;c++) xl[c] = 0.f;
  } else {
    const float* xq = xp - (size_t)Cc*Nn;
    #pragma unroll
    for (int c=0;c<32;c++) xl[c] = xq[(size_t)c*Nn];
  }
  float xgv[32];
  for (int c=0;c<32;c++) {
    float f = sfb[c], g = sgb[c];
    #pragma unroll
    for (int cp=0;cp<32;cp++) {
      f += xl[cp]*sfw[(c*32+cp)*2] + xr[cp]*sfw[(c*32+cp)*2+1];
      g += xl[cp]*sgw[(c*32+cp)*2] + xr[cp]*sgw[(c*32+cp)*2+1];
    }
    xgv[c] = tanhf(f) * sigm(g);
  }
  float* xgp = xg + btl*Cc*Nn + n;
  #pragma unroll
  for (int c=0;c<32;c++) xgp[(size_t)c*Nn] = xgv[c];
  float* gp = gout + btl*Cc*Nn + n;
  for (int o=0;o<32;o++) {
    float s = sgcb[o];
    #pragma unroll
    for (int c=0;c<32;c++) s += sw0[o*32+c]*xgv[c];
    gp[(size_t)o*Nn] = s;
  }
}

// ---------------- support GEMM via split-bf16 MFMA ----------------
__launch_bounds__(256)
__global__ void k_supmfma(const float* __restrict__ X,
                          const unsigned short* __restrict__ ShiT,
                          const unsigned short* __restrict__ SloT,
                          const float* __restrict__ gcw, int pslot,
                          float* __restrict__ Y, float* __restrict__ gout, int storeY) {
  __shared__ unsigned char smem[64*132*4];      // pool: staging (30720B) then sY (33792B)
  __shared__ float sW[1024];
  unsigned short* sXhi = (unsigned short*)smem;                 // 64*40
  unsigned short* sXlo = sXhi + 2560;
  unsigned short* sShi = sXlo + 2560;                           // 128*40
  unsigned short* sSlo = sShi + 5120;
  float* sY = (float*)smem;                                     // 64*132 (after K loop)
#define MW 40

  const int tid  = threadIdx.x;
  const int bt2  = blockIdx.x >> 2;
  const int colg = blockIdx.x & 3;
  const int bt0  = bt2*2;
  const int n0   = colg*128;
  const int lane = tid & 63, wv = tid >> 6;
  const int kb   = (lane >> 4)*8;

  for (int l = tid; l < 1024; l += 256)
    sW[l] = gcw[(l>>5)*224 + pslot*32 + (l&31)];

  f32x4 acc[4][2];
  #pragma unroll
  for (int i=0;i<4;i++) {
    #pragma unroll
    for (int j=0;j<2;j++) { acc[i][j].x=0.f; acc[i][j].y=0.f; acc[i][j].z=0.f; acc[i][j].w=0.f; }
  }

  const int sm  = tid >> 2;              // X stage: row 0..63
  const int skp = (tid & 3)*8;           // k part
  const size_t xrow = ((size_t)(bt0 + (sm>>5))*Cc + (sm&31))*Nn;
  const int sn  = tid >> 1;              // S stage: col-row 0..127
  const int shp = (tid & 1)*16;          // 16-k half

  for (int kc = 0; kc < 16; kc++) {
    const int k0 = kc*32;
    {
      float4 a0 = *reinterpret_cast<const float4*>(&X[xrow + k0 + skp]);
      float4 a1 = *reinterpret_cast<const float4*>(&X[xrow + k0 + skp + 4]);
      float v[8] = {a0.x,a0.y,a0.z,a0.w,a1.x,a1.y,a1.z,a1.w};
      unsigned int h[8], l[8];
      #pragma unroll
      for (int i=0;i<8;i++) {
        h[i] = f2bf(v[i]);
        l[i] = f2bf(v[i] - bf2f(h[i]));
      }
      uint4 H = { h[0]|(h[1]<<16), h[2]|(h[3]<<16), h[4]|(h[5]<<16), h[6]|(h[7]<<16) };
      uint4 L = { l[0]|(l[1]<<16), l[2]|(l[3]<<16), l[4]|(l[5]<<16), l[6]|(l[7]<<16) };
      *reinterpret_cast<uint4*>(&sXhi[sm*MW + skp]) = H;
      *reinterpret_cast<uint4*>(&sXlo[sm*MW + skp]) = L;
    }
    {
      const size_t srow = (size_t)(n0 + sn)*512 + k0 + shp;
      *reinterpret_cast<uint4*>(&sShi[sn*MW + shp])     = *reinterpret_cast<const uint4*>(&ShiT[srow]);
      *reinterpret_cast<uint4*>(&sShi[sn*MW + shp + 8]) = *reinterpret_cast<const uint4*>(&ShiT[srow + 8]);
      *reinterpret_cast<uint4*>(&sSlo[sn*MW + shp])     = *reinterpret_cast<const uint4*>(&SloT[srow]);
      *reinterpret_cast<uint4*>(&sSlo[sn*MW + shp + 8]) = *reinterpret_cast<const uint4*>(&SloT[srow + 8]);
    }
    __syncthreads();
    short8v bhi[2], blo[2];
    #pragma unroll
    for (int ct=0; ct<2; ct++) {
      int col = wv*32 + ct*16 + (lane & 15);
      bhi[ct] = *reinterpret_cast<const short8v*>(&sShi[col*MW + kb]);
      blo[ct] = *reinterpret_cast<const short8v*>(&sSlo[col*MW + kb]);
    }
    #pragma unroll
    for (int rt=0; rt<4; rt++) {
      int row = rt*16 + (lane & 15);
      short8v ahi = *reinterpret_cast<const short8v*>(&sXhi[row*MW + kb]);
      short8v alo = *reinterpret_cast<const short8v*>(&sXlo[row*MW + kb]);
      #pragma unroll
      for (int ct=0; ct<2; ct++) {
        acc[rt][ct] = __builtin_amdgcn_mfma_f32_16x16x32_bf16(ahi, bhi[ct], acc[rt][ct], 0, 0, 0);
        acc[rt][ct] = __builtin_amdgcn_mfma_f32_16x16x32_bf16(ahi, blo[ct], acc[rt][ct], 0, 0, 0);
        acc[rt][ct] = __builtin_amdgcn_mfma_f32_16x16x32_bf16(alo, bhi[ct], acc[rt][ct], 0, 0, 0);
      }
    }
    __syncthreads();
  }
  #pragma unroll
  for (int rt=0; rt<4; rt++) {
    #pragma unroll
    for (int ct=0; ct<2; ct++) {
      int col = wv*32 + ct*16 + (lane & 15);
      int rbase = rt*16 + (lane >> 4)*4;
      sY[(rbase+0)*132 + col] = acc[rt][ct].x;
      sY[(rbase+1)*132 + col] = acc[rt][ct].y;
      sY[(rbase+2)*132 + col] = acc[rt][ct].z;
      sY[(rbase+3)*132 + col] = acc[rt][ct].w;
    }
  }
  __syncthreads();
  if (storeY) {
    for (int e = tid; e < 2048; e += 256) {
      int m = e >> 5, c4 = (e & 31)*4;
      float4 v = *reinterpret_cast<const float4*>(&sY[m*132 + c4]);
      *reinterpret_cast<float4*>(&Y[((size_t)(bt0 + (m>>5))*Cc + (m&31))*Nn + n0 + c4]) = v;
    }
  }
  {
    int tx = tid & 31, ty = tid >> 5;
    for (int btl = 0; btl < 2; btl++) {
      float og[4][4];
      #pragma unroll
      for (int i=0;i<4;i++) { og[i][0]=0.f; og[i][1]=0.f; og[i][2]=0.f; og[i][3]=0.f; }
      #pragma unroll 8
      for (int c = 0; c < 32; c++) {
        float4 yv = *reinterpret_cast<const float4*>(&sY[(btl*32 + c)*132 + tx*4]);
        float w0 = sW[((ty<<2)+0)*32 + c];
        float w1 = sW[((ty<<2)+1)*32 + c];
        float w2 = sW[((ty<<2)+2)*32 + c];
        float w3 = sW[((ty<<2)+3)*32 + c];
        og[0][0]+=w0*yv.x; og[0][1]+=w0*yv.y; og[0][2]+=w0*yv.z; og[0][3]+=w0*yv.w;
        og[1][0]+=w1*yv.x; og[1][1]+=w1*yv.y; og[1][2]+=w1*yv.z; og[1][3]+=w1*yv.w;
        og[2][0]+=w2*yv.x; og[2][1]+=w2*yv.y; og[2][2]+=w2*yv.z; og[2][3]+=w2*yv.w;
        og[3][0]+=w3*yv.x; og[3][1]+=w3*yv.y; og[3][2]+=w3*yv.z; og[3][3]+=w3*yv.w;
      }
      float* gp = gout + (size_t)(bt0+btl)*Cc*Nn + n0 + (tx<<2);
      #pragma unroll
      for (int i=0;i<4;i++) {
        float4 cur = *reinterpret_cast<float4*>(gp + (size_t)((ty<<2)+i)*Nn);
        cur.x += og[i][0]; cur.y += og[i][1]; cur.z += og[i][2]; cur.w += og[i][3];
        *reinterpret_cast<float4*>(gp + (size_t)((ty<<2)+i)*Nn) = cur;
      }
    }
  }
#undef MW
}

// ---------------- skip gather: skipK[b,k,c,t] (+)= xg_q[btl,c,node] ----------------
__global__ void k_skipgather(const float* __restrict__ xg, const int* __restrict__ miss,
                             float* __restrict__ skipK, int chunk, int first) {
  int idx = blockIdx.x*256 + threadIdx.x;
  if (idx >= BPC*Kk*Tt) return;
  int t = idx % Tt;
  int k = (idx / Tt) % Kk;
  int bloc = idx / (Tt*Kk);
  int bg = chunk*BPC + bloc;
  int node = miss[bg*Kk + k];
  const float* xp = xg + (((size_t)bloc*Tt + t)*Cc)*Nn + node;
  float* sp = skipK + (((size_t)bg*Kk + k)*Cc)*Tt + t;
  #pragma unroll
  for (int c=0;c<32;c++) {
    float v = xp[(size_t)c*Nn];
    sp[(size_t)c*Tt] = first ? v : (sp[(size_t)c*Tt] + v);
  }
}

// ---------------- fused ingru + xfold: Xs = iw@gout + ib ; x += gout (one gout pass) ----------------
__global__ void k_ingruxf(const float* __restrict__ gout, const float* __restrict__ iw,
                          const float* __restrict__ ib2, float* __restrict__ Xs,
                          float* __restrict__ x, int chunk) {
  size_t idx = (size_t)blockIdx.x*256 + threadIdx.x;
  if (idx >= BTNc) return;
  int n = idx & 511;
  size_t btl = idx >> 9;
  int b = chunk*BPC + (int)(btl / Tt), t = (int)(btl % Tt);
  const float* gp = gout + btl*Cc*Nn + n;
  float* xp = x + ((size_t)chunk*BTc + btl)*Cc*Nn + n;
  float s = ib2[0];
  #pragma unroll
  for (int c=0;c<Cc;c++) {
    float g = gp[(size_t)c*Nn];
    s += iw[c]*g;
    xp[(size_t)c*Nn] += g;
  }
  Xs[((size_t)t*Bb + b)*Nn + n] = s;
}

// ---------------- GRU v7: wave-decoupled (per-batch flags, no __syncthreads in t-loop) ----------------
// Round-9 diagnosis: block-wide barrier coupled 8 independent batch-waves, 2x/step. Now:
// wave b owns batch b; per-(block,batch) flags; bypass loads go straight to registers
// (butterfly reduce leaves full sums in every lane); only lane 0 stores + signals.
__launch_bounds__(512, 1)
__global__ void k_gru7(const float* __restrict__ Xs, const float* __restrict__ input,
                       const float* __restrict__ wpack,
                       const float* __restrict__ zb, const float* __restrict__ rb,
                       const float* __restrict__ hb,
                       float* __restrict__ xh_g,      // [b][ xin 0:512 | h 512:1024 ]
                       float* __restrict__ rh_g,      // [b][512]
                       float* __restrict__ outs,
                       int* __restrict__ flags) {     // [(b*64+sl)*32]
  __shared__ float wl[8*3072];   // 96KB weights only
  const int tid = threadIdx.x;
  const int sl  = blockIdx.x;
  const int n0  = sl*8;
  const int b   = tid >> 6;      // wave = batch
  const int q   = tid & 63;

  // stage weights once
  {
    const float4* src = reinterpret_cast<const float4*>(wpack + (size_t)sl*24576);
    float4* dst = reinterpret_cast<float4*>(wl);
    #pragma unroll 4
    for (int i = tid; i < 6144; i += 512) dst[i] = src[i];
  }
  // t=0 init: lanes 0..7 of wave b write h=0, xin for batch b, own cols
  if (q < 8) {
    int nn = n0 + q;
    float Xi = Xs[(size_t)b*Nn + nn];
    float Mi = input[(((size_t)b*7+1)*Tt + 0)*Nn + nn];
    sysstore(xh_g + b*1024 + 512 + nn, 0.f);
    sysstore(xh_g + b*1024 + nn, sigm(Xi*Mi));
  }
  __syncthreads();   // weights visible to all waves (only sync in the kernel)
  asm volatile("s_waitcnt vmcnt(0)" ::: "memory");
  if (q == 0) flagstore(flags + (b*64 + sl)*32, 1);

  const int* pollfl = flags + (b*64 + q)*32;   // lane q polls block q, batch b
  int* myfl = flags + (b*64 + sl)*32;

  float zbv[8], rbv[8], hbv[8];
  #pragma unroll
  for (int c=0;c<8;c++) { zbv[c]=zb[n0+c]; rbv[c]=rb[n0+c]; hbv[c]=hb[n0+c]; }

  const float* bp = xh_g + b*1024;
  const float* rp = rh_g + b*512;

  for (int t = 0; t < Tt; t++) {
    // prefetch next-step Xs/M (regular cached loads; uniform across wave)
    float4 xiA, xiB, miA, miB;
    {
      int tp = (t+1 < Tt) ? (t+1) : t;
      const float* xsp = Xs + ((size_t)tp*Bb + b)*Nn + n0;
      const float* mip = input + (((size_t)b*7+1)*Tt + tp)*Nn + n0;
      xiA = *reinterpret_cast<const float4*>(xsp);
      xiB = *reinterpret_cast<const float4*>(xsp + 4);
      miA = *reinterpret_cast<const float4*>(mip);
      miB = *reinterpret_cast<const float4*>(mip + 4);
    }
    // ---- wait: all blocks finished phase B of t-1 (or init) for batch b ----
    {
      int tgt = 1 + 2*t;
      while (!__all(flagload(pollfl) >= tgt)) __builtin_amdgcn_s_sleep(1);
    }
    // ---- load xin|h straight to registers (bypass), one drain ----
    f32x2 xv[8]; f32x4 h0v, h1v;
    asm volatile(
      "global_load_dwordx2 %0, %10, off sc0 sc1\n\t"
      "global_load_dwordx2 %1, %11, off sc0 sc1\n\t"
      "global_load_dwordx2 %2, %12, off sc0 sc1\n\t"
      "global_load_dwordx2 %3, %13, off sc0 sc1\n\t"
      "global_load_dwordx2 %4, %14, off sc0 sc1\n\t"
      "global_load_dwordx2 %5, %15, off sc0 sc1\n\t"
      "global_load_dwordx2 %6, %16, off sc0 sc1\n\t"
      "global_load_dwordx2 %7, %17, off sc0 sc1\n\t"
      "global_load_dwordx4 %8, %18, off sc0 sc1\n\t"
      "global_load_dwordx4 %9, %19, off sc0 sc1\n\t"
      "s_waitcnt vmcnt(0)"
      : "=&v"(xv[0]), "=&v"(xv[1]), "=&v"(xv[2]), "=&v"(xv[3]),
        "=&v"(xv[4]), "=&v"(xv[5]), "=&v"(xv[6]), "=&v"(xv[7]),
        "=&v"(h0v), "=&v"(h1v)
      : "v"(bp + 0*128 + q*2), "v"(bp + 1*128 + q*2), "v"(bp + 2*128 + q*2), "v"(bp + 3*128 + q*2),
        "v"(bp + 4*128 + q*2), "v"(bp + 5*128 + q*2), "v"(bp + 6*128 + q*2), "v"(bp + 7*128 + q*2),
        "v"(bp + 512 + n0), "v"(bp + 512 + n0 + 4)
      : "memory");
    float hold[8] = {h0v.x, h0v.y, h0v.z, h0v.w, h1v.x, h1v.y, h1v.z, h1v.w};
    // ---- phase A: z, r (K=1024), hx (K=512) ----
    float az[8], ar[8], ax[8];
    #pragma unroll
    for (int c=0;c<8;c++) { az[c]=0.f; ar[c]=0.f; ax[c]=0.f; }
    #pragma unroll
    for (int i = 0; i < 8; i++) {
      int k = i*128 + q*2;
      #pragma unroll
      for (int c = 0; c < 8; c++) {
        float2 wz = *reinterpret_cast<const float2*>(wl + c*3072 + k);
        float2 wr = *reinterpret_cast<const float2*>(wl + c*3072 + 1024 + k);
        az[c] += xv[i].x*wz.x + xv[i].y*wz.y;
        ar[c] += xv[i].x*wr.x + xv[i].y*wr.y;
      }
    }
    #pragma unroll
    for (int i = 0; i < 4; i++) {
      int k = i*128 + q*2;
      #pragma unroll
      for (int c = 0; c < 8; c++) {
        float2 wx = *reinterpret_cast<const float2*>(wl + c*3072 + 2048 + k);
        ax[c] += xv[i].x*wx.x + xv[i].y*wx.y;
      }
    }
    #pragma unroll
    for (int d = 1; d < 64; d <<= 1) {
      #pragma unroll
      for (int c = 0; c < 8; c++) {
        az[c] += __shfl_xor(az[c], d);
        ar[c] += __shfl_xor(ar[c], d);
        ax[c] += __shfl_xor(ax[c], d);
      }
    }
    // all lanes now hold full sums (butterfly) — compute gates uniformly
    float zs[8], rh[8];
    #pragma unroll
    for (int c = 0; c < 8; c++) {
      zs[c] = sigm(az[c] + zbv[c]);
      float r = sigm(ar[c] + rbv[c]);
      rh[c] = r * hold[c];
    }
    if (q == 0) {
      f32x4 r0 = {rh[0],rh[1],rh[2],rh[3]};
      f32x4 r1 = {rh[4],rh[5],rh[6],rh[7]};
      byp_store4(rh_g + b*512 + n0,     r0);
      byp_store4(rh_g + b*512 + n0 + 4, r1);
      asm volatile("s_waitcnt vmcnt(0)" ::: "memory");
      flagstore(myfl, 2 + 2*t);
    }
    // ---- wait: all blocks finished phase A for batch b ----
    {
      int tgt = 2 + 2*t;
      while (!__all(flagload(pollfl) >= tgt)) __builtin_amdgcn_s_sleep(1);
    }
    // ---- load rh straight to registers ----
    f32x2 rv[4];
    asm volatile(
      "global_load_dwordx2 %0, %4, off sc0 sc1\n\t"
      "global_load_dwordx2 %1, %5, off sc0 sc1\n\t"
      "global_load_dwordx2 %2, %6, off sc0 sc1\n\t"
      "global_load_dwordx2 %3, %7, off sc0 sc1\n\t"
      "s_waitcnt vmcnt(0)"
      : "=&v"(rv[0]), "=&v"(rv[1]), "=&v"(rv[2]), "=&v"(rv[3])
      : "v"(rp + 0*128 + q*2), "v"(rp + 1*128 + q*2), "v"(rp + 2*128 + q*2), "v"(rp + 3*128 + q*2)
      : "memory");
    // ---- phase B: hh (K=512) + combine ----
    float ah[8];
    #pragma unroll
    for (int c=0;c<8;c++) ah[c]=0.f;
    #pragma unroll
    for (int i = 0; i < 4; i++) {
      int k = i*128 + q*2;
      #pragma unroll
      for (int c = 0; c < 8; c++) {
        float2 wh = *reinterpret_cast<const float2*>(wl + c*3072 + 2560 + k);
        ah[c] += rv[i].x*wh.x + rv[i].y*wh.y;
      }
    }
    #pragma unroll
    for (int d = 1; d < 64; d <<= 1) {
      #pragma unroll
      for (int c = 0; c < 8; c++) ah[c] += __shfl_xor(ah[c], d);
    }
    float hn[8];
    #pragma unroll
    for (int c = 0; c < 8; c++) {
      float ht = tanhf(ax[c] + ah[c] + hbv[c]);
      hn[c] = (1.f - zs[c])*hold[c] + zs[c]*ht;
    }
    if (q == 0) {
      f32x4 h0 = {hn[0],hn[1],hn[2],hn[3]};
      f32x4 h1 = {hn[4],hn[5],hn[6],hn[7]};
      *reinterpret_cast<f32x4*>(&outs[((size_t)t*Bb + b)*Nn + n0])     = h0;
      *reinterpret_cast<f32x4*>(&outs[((size_t)t*Bb + b)*Nn + n0 + 4]) = h1;
      byp_store4(xh_g + b*1024 + 512 + n0,     h0);
      byp_store4(xh_g + b*1024 + 512 + n0 + 4, h1);
      if (t+1 < Tt) {
        f32x4 x0, x1;
        x0.x = sigm(xiA.x*miA.x + hn[0]*(1.f - miA.x));
        x0.y = sigm(xiA.y*miA.y + hn[1]*(1.f - miA.y));
        x0.z = sigm(xiA.z*miA.z + hn[2]*(1.f - miA.z));
        x0.w = sigm(xiA.w*miA.w + hn[3]*(1.f - miA.w));
        x1.x = sigm(xiB.x*miB.x + hn[4]*(1.f - miB.x));
        x1.y = sigm(xiB.y*miB.y + hn[5]*(1.f - miB.y));
        x1.z = sigm(xiB.z*miB.z + hn[6]*(1.f - miB.z));
        x1.w = sigm(xiB.w*miB.w + hn[7]*(1.f - miB.w));
        byp_store4(xh_g + b*1024 + n0,     x0);
        byp_store4(xh_g + b*1024 + n0 + 4, x1);
      }
      asm volatile("s_waitcnt vmcnt(0)" ::: "memory");
      flagstore(myfl, 3 + 2*t);
    }
  }
}

// ---------------- x += outs*rw + rb (after GRU) ----------------
__global__ void k_xre(float* __restrict__ x, const float* __restrict__ outs,
                      const float* __restrict__ rw, const float* __restrict__ rb2) {
  size_t idx = (size_t)blockIdx.x*256 + threadIdx.x;
  if (idx >= BTCN) return;
  int n = idx & 511;
  int c = (int)((idx >> 9) & 31);
  size_t bt = idx >> 14;
  int b = (int)(bt / Tt), t = (int)(bt % Tt);
  float o = outs[((size_t)t*Bb + b)*Nn + n];
  x[idx] += o*rw[c] + rb2[c];
}

// ---------------- head: relu(skipK) -> end1 relu -> end2 ----------------
__launch_bounds__(256)
__global__ void k_head(const float* __restrict__ skipK,
                       const float* __restrict__ e1w, const float* __restrict__ e1b,
                       const float* __restrict__ e2w, const float* __restrict__ e2b,
                       float* __restrict__ out) {
  __shared__ float sw[2048], sb[64], s2[64];
  for (int l = threadIdx.x; l < 2048; l += 256) sw[l] = e1w[l];
  if (threadIdx.x < 64) { sb[threadIdx.x] = e1b[threadIdx.x]; s2[threadIdx.x] = e2w[threadIdx.x]; }
  __syncthreads();
  int idx = blockIdx.x*256 + threadIdx.x;
  if (idx >= Bb*Kk*Tt) return;
  int t = idx % Tt;
  int k = (idx / Tt) % Kk;
  int b = idx / (Tt*Kk);
  const float* sp = skipK + (((size_t)b*Kk + k)*Cc)*Tt + t;
  float in[32];
  #pragma unroll
  for (int c=0;c<32;c++) in[c] = fmaxf(sp[(size_t)c*Tt], 0.f);
  float acc = e2b[0];
  for (int o=0;o<64;o++) {
    float s = sb[o];
    #pragma unroll
    for (int c=0;c<32;c++) s += sw[o*32+c]*in[c];
    acc += s2[o]*fmaxf(s, 0.f);
  }
  out[idx] = acc;
}

extern "C" void kernel_launch(void* const* d_in, const int* in_sizes, int n_in,
                              void* d_out, int out_size, void* d_ws, size_t ws_size,
                              hipStream_t stream) {
  const float* input = (const float*)d_in[0];
  const int*   miss  = (const int*)  d_in[1];
  const float* sup0  = (const float*)d_in[2];
  const float* sup1  = (const float*)d_in[3];
  const float* nv1   = (const float*)d_in[4];
  const float* nv2   = (const float*)d_in[5];
  const float* skw   = (const float*)d_in[6];
  const float* skb   = (const float*)d_in[7];
  const float* fw    = (const float*)d_in[8];
  const float* fb    = (const float*)d_in[9];
  const float* gw    = (const float*)d_in[10];
  const float* gb    = (const float*)d_in[11];
  const float* gcw   = (const float*)d_in[12];
  const float* gcb   = (const float*)d_in[13];
  const float* iw    = (const float*)d_in[14];
  const float* ib2   = (const float*)d_in[15];
  const float* rw    = (const float*)d_in[16];
  const float* rb2   = (const float*)d_in[17];
  const float* zl    = (const float*)d_in[18];
  const float* zb    = (const float*)d_in[19];
  const float* rl    = (const float*)d_in[20];
  const float* rb    = (const float*)d_in[21];
  const float* hl    = (const float*)d_in[22];
  const float* hb    = (const float*)d_in[23];
  const float* e1w   = (const float*)d_in[24];
  const float* e1b   = (const float*)d_in[25];
  const float* e2w   = (const float*)d_in[26];
  const float* e2b   = (const float*)d_in[27];
  float* out = (float*)d_out;

  float* p     = (float*)d_ws;
  float* x     = p; p += BTCN;
  float* xg    = p; p += BTCNc;
  float* tmp1  = p; p += BTCNc;
  float* gout  = p; p += BTCNc;
  float* skipK = p; p += (size_t)Bb*Kk*Cc*Tt;
  float* adp   = p; p += (size_t)Nn*Nn;
  float* wpack = p; p += (size_t)GRUB*8*3072;
  unsigned short* ShiT = (unsigned short*)p; p += (size_t)(3*512*512)/2;
  unsigned short* SloT = (unsigned short*)p; p += (size_t)(3*512*512)/2;
  float* Xs    = p; p += (size_t)Tt*Bb*Nn;
  float* outs  = p; p += (size_t)Tt*Bb*Nn;
  float* xh_g  = p; p += Bb*1024;
  float* rh_g  = p; p += Bb*512;
  int*   flags = (int*)p; p += (size_t)Bb*GRUB*32;

  k_wt2<<<(GRUB*8*3072 + 255)/256, 256, 0, stream>>>(zl, rl, hl, wpack);
  k_adp<<<Nn, 256, 0, stream>>>(nv1, nv2, adp);
  k_sprep<<<(3*512*512 + 255)/256, 256, 0, stream>>>(sup0, sup1, adp, ShiT, SloT);
  k_intransform<<<(int)((BTN + 255)/256), 256, 0, stream>>>(input, skw, skb, x);

  for (int layer = 0; layer < Ll; layer++) {
    for (int chunk = 0; chunk < NCH; chunk++) {
      k_fgconv<<<(int)((BTNc + 255)/256), 256, 0, stream>>>(
          x, fw + layer*2048, fb + layer*32, gw + layer*2048, gb + layer*32,
          gcw + layer*32*224, gcb + layer*32, xg, gout, chunk);
      for (int s = 0; s < 3; s++) {
        k_supmfma<<<dim3((BTc/2)*4), 256, 0, stream>>>(
            xg,   ShiT + s*262144, SloT + s*262144, gcw + layer*32*224, 2*s+1, tmp1, gout, 1);
        k_supmfma<<<dim3((BTc/2)*4), 256, 0, stream>>>(
            tmp1, ShiT + s*262144, SloT + s*262144, gcw + layer*32*224, 2*s+2, tmp1, gout, 0);
      }
      k_skipgather<<<(BPC*Kk*Tt + 255)/256, 256, 0, stream>>>(xg, miss, skipK, chunk, layer == 0 ? 1 : 0);
      k_ingruxf<<<(int)((BTNc + 255)/256), 256, 0, stream>>>(gout, iw, ib2, Xs, x, chunk);
    }
    (void)hipMemsetAsync(flags, 0, (size_t)Bb*GRUB*32*sizeof(int), stream);
    k_gru7<<<dim3(GRUB), dim3(512), 0, stream>>>(
        Xs, input, wpack, zb, rb, hb, xh_g, rh_g, outs, flags);
    k_xre<<<(int)((BTCN + 255)/256), 256, 0, stream>>>(x, outs, rw, rb2);
  }
  k_head<<<(Bb*Kk*Tt + 255)/256, 256, 0, stream>>>(skipK, e1w, e1b, e2w, e2b, out);
}